// Round 1
// baseline (4829.652 us; speedup 1.0000x reference)
//
#include <hip/hip_runtime.h>
#include <math.h>

// Problem constants (fixed by setup_inputs)
#define B_   8
#define C_   256
#define HW_  4096      // 64*64
#define N_   32768     // B*H*W
#define K_   8192
#define BN   32        // rows per block in argmin kernel
#define BK   64        // codes per k-tile

// ---------------- zn2[n] = sum_c z[n,c]^2 (fp64 accum, rounded to f32) -------
__global__ __launch_bounds__(256) void vq_zn2_kernel(const float* __restrict__ z,
                                                     float* __restrict__ zn2g) {
    int n = blockIdx.x * 256 + threadIdx.x;       // grid = 128 blocks
    int b = n >> 12;
    int hw = n & 4095;
    const float* p = z + (size_t)b * C_ * HW_ + hw;
    double acc = 0.0;
    #pragma unroll 8
    for (int c = 0; c < C_; ++c) {
        float v = p[(size_t)c * HW_];
        acc += (double)v * (double)v;
    }
    zn2g[n] = (float)acc;
}

// ---------------- e2[k] = sum_c cb[k,c]^2 ------------------------------------
__global__ __launch_bounds__(256) void vq_e2_kernel(const float* __restrict__ cb,
                                                    float* __restrict__ e2g) {
    int lane = threadIdx.x & 63;
    int w = threadIdx.x >> 6;
    int k = blockIdx.x * 4 + w;                   // grid = 2048 blocks
    const float4 v = *reinterpret_cast<const float4*>(cb + (size_t)k * C_ + lane * 4);
    double acc = (double)v.x * v.x + (double)v.y * v.y
               + (double)v.z * v.z + (double)v.w * v.w;
    #pragma unroll
    for (int off = 32; off >= 1; off >>= 1) acc += __shfl_xor(acc, off);
    if (lane == 0) e2g[k] = (float)acc;
}

// ---------------- fused distance + argmin ------------------------------------
// d_k = fl( fl(zn2 + e2_k) - 2*fl(s_k) ), s_k accumulated in fp64.
// Tie-break: lowest k (matches np/jnp.argmin first-occurrence).
__global__ __launch_bounds__(256) void vq_argmin_kernel(const float* __restrict__ z,
                                                        const float* __restrict__ cb,
                                                        const float* __restrict__ e2g,
                                                        const float* __restrict__ zn2g,
                                                        int* __restrict__ idxg) {
    __shared__ float zt[C_][BN];   // 32 KB, z tile transposed [c][n]
    __shared__ float et[64][BK];   // 16 KB, codebook chunk transposed [c][k]
    const int tid = threadIdx.x;
    const int n0 = blockIdx.x * BN;               // grid = 1024 blocks
    const int b = n0 >> 12;
    const int hw0 = n0 & 4095;

    // stage z tile: [c][n] layout, coalesced reads (32 consecutive hw per c)
    {
        const int nn = tid & 31;
        const int c8 = tid >> 5;
        #pragma unroll
        for (int j = 0; j < 32; ++j) {
            const int c = j * 8 + c8;
            zt[c][nn] = z[(size_t)(b * C_ + c) * HW_ + hw0 + nn];
        }
    }
    const int cg = tid & 15;       // code-group within row-group (16 lanes)
    const int rg = tid >> 4;       // row-group (2 rows each)
    const int r0 = rg * 2;
    __syncthreads();

    const float zn2a = zn2g[n0 + r0];
    const float zn2b = zn2g[n0 + r0 + 1];
    float dmin0 = INFINITY, dmin1 = INFINITY;
    int imin0 = 0, imin1 = 0;

    const int kk = tid >> 2;       // staging: code row this thread loads
    const int c4 = (tid & 3) * 16; // staging: c-offset this thread loads

    for (int kt = 0; kt < K_; kt += BK) {
        double s00 = 0, s01 = 0, s02 = 0, s03 = 0;
        double s10 = 0, s11 = 0, s12 = 0, s13 = 0;
        for (int cc = 0; cc < C_; cc += 64) {
            __syncthreads();   // protect et from previous chunk's readers
            {
                const float* src = cb + (size_t)(kt + kk) * C_ + cc + c4;
                #pragma unroll
                for (int j = 0; j < 16; j += 4) {
                    const float4 v = *reinterpret_cast<const float4*>(src + j);
                    et[c4 + j + 0][kk] = v.x;
                    et[c4 + j + 1][kk] = v.y;
                    et[c4 + j + 2][kk] = v.z;
                    et[c4 + j + 3][kk] = v.w;
                }
            }
            __syncthreads();
            #pragma unroll 4
            for (int c2 = 0; c2 < 64; ++c2) {
                const float2 zv = *reinterpret_cast<const float2*>(&zt[cc + c2][r0]);
                const float4 ev = *reinterpret_cast<const float4*>(&et[c2][cg * 4]);
                const double z0 = (double)zv.x, z1 = (double)zv.y;
                const double e0 = (double)ev.x, e1 = (double)ev.y;
                const double e2 = (double)ev.z, e3 = (double)ev.w;
                s00 += z0 * e0; s01 += z0 * e1; s02 += z0 * e2; s03 += z0 * e3;
                s10 += z1 * e0; s11 += z1 * e1; s12 += z1 * e2; s13 += z1 * e3;
            }
        }
        // distances for this k-tile, mimicking reference rounding exactly
        const int kbase = kt + cg * 4;
        const float sf0[4] = {(float)s00, (float)s01, (float)s02, (float)s03};
        const float sf1[4] = {(float)s10, (float)s11, (float)s12, (float)s13};
        #pragma unroll
        for (int j = 0; j < 4; ++j) {
            const int k = kbase + j;
            const float e2k = e2g[k];
            const float d0 = (zn2a + e2k) - 2.0f * sf0[j];
            const float d1 = (zn2b + e2k) - 2.0f * sf1[j];
            if (d0 < dmin0) { dmin0 = d0; imin0 = k; }   // strict < : first-min
            if (d1 < dmin1) { dmin1 = d1; imin1 = k; }
        }
    }
    // reduce across the 16 cg-lanes of each row group (contiguous in the wave)
    #pragma unroll
    for (int off = 8; off >= 1; off >>= 1) {
        const float od0 = __shfl_xor(dmin0, off);
        const int   oi0 = __shfl_xor(imin0, off);
        const float od1 = __shfl_xor(dmin1, off);
        const int   oi1 = __shfl_xor(imin1, off);
        if (od0 < dmin0 || (od0 == dmin0 && oi0 < imin0)) { dmin0 = od0; imin0 = oi0; }
        if (od1 < dmin1 || (od1 == dmin1 && oi1 < imin1)) { dmin1 = od1; imin1 = oi1; }
    }
    if (cg == 0) {
        idxg[n0 + r0]     = imin0;
        idxg[n0 + r0 + 1] = imin1;
    }
}

// ---------------- z_q (STE arithmetic mimic) + loss sum ----------------------
__global__ __launch_bounds__(256) void vq_zq_loss_kernel(const float* __restrict__ z,
                                                         const float* __restrict__ cb,
                                                         const int* __restrict__ idxg,
                                                         float* __restrict__ out,
                                                         double* __restrict__ loss_sum) {
    const size_t i = (size_t)blockIdx.x * 256 + threadIdx.x;  // grid = 32768 blocks
    const int hw = (int)(i & 4095);
    const int bc = (int)(i >> 12);
    const int c = bc & 255;
    const int b = bc >> 8;
    const int n = (b << 12) + hw;
    const float zv = z[i];
    const int k = idxg[n];
    const float cv = cb[(size_t)k * C_ + c];
    const float t = cv - zv;          // fl(z_q - z)
    out[i] = zv + t;                  // fl(z + fl(z_q - z)) : STE output
    double sq = (double)t * (double)t;
    #pragma unroll
    for (int off = 32; off >= 1; off >>= 1) sq += __shfl_xor(sq, off);
    __shared__ double ls[4];
    const int lane = threadIdx.x & 63, wid = threadIdx.x >> 6;
    if (lane == 0) ls[wid] = sq;
    __syncthreads();
    if (threadIdx.x == 0) atomicAdd(loss_sum, ls[0] + ls[1] + ls[2] + ls[3]);
}

// ---------------- finalize: loss scalar + indices as float -------------------
__global__ __launch_bounds__(256) void vq_final_kernel(const int* __restrict__ idxg,
                                                       const double* __restrict__ loss_sum,
                                                       float* __restrict__ out) {
    const int i = blockIdx.x * 256 + threadIdx.x;             // grid = 128 blocks
    out[(size_t)(N_ * C_ * B_ / B_) * 0 + 8388609 + i] = (float)idxg[i];
    if (i == 0) out[8388608] = (float)(1.25 * (*loss_sum) / 8388608.0);
}

extern "C" void kernel_launch(void* const* d_in, const int* in_sizes, int n_in,
                              void* d_out, int out_size, void* d_ws, size_t ws_size,
                              hipStream_t stream) {
    const float* z  = (const float*)d_in[0];   // [8,256,64,64]
    const float* cb = (const float*)d_in[1];   // [8192,256]
    float* out = (float*)d_out;                // [z_q 8388608][loss 1][idx 32768]
    char* ws = (char*)d_ws;
    double* loss_sum = (double*)ws;                       // 8 B
    float* e2g  = (float*)(ws + 64);                      // 8192 f32
    float* zn2g = (float*)(ws + 64 + 32768);              // 32768 f32
    int*   idxg = (int*)(ws + 64 + 32768 + 131072);       // 32768 i32

    hipMemsetAsync(loss_sum, 0, sizeof(double), stream);
    hipLaunchKernelGGL(vq_zn2_kernel, dim3(N_ / 256), dim3(256), 0, stream, z, zn2g);
    hipLaunchKernelGGL(vq_e2_kernel, dim3(K_ / 4), dim3(256), 0, stream, cb, e2g);
    hipLaunchKernelGGL(vq_argmin_kernel, dim3(N_ / BN), dim3(256), 0, stream,
                       z, cb, e2g, zn2g, idxg);
    hipLaunchKernelGGL(vq_zq_loss_kernel, dim3((B_ * C_ * HW_) / 256), dim3(256), 0, stream,
                       z, cb, idxg, out, loss_sum);
    hipLaunchKernelGGL(vq_final_kernel, dim3(N_ / 256), dim3(256), 0, stream,
                       idxg, loss_sum, out);
}

// Round 2
// 1015.345 us; speedup vs baseline: 4.7567x; 4.7567x over previous
//
#include <hip/hip_runtime.h>
#include <hip/hip_bf16.h>
#include <math.h>

typedef unsigned short u16;
typedef unsigned int u32;
typedef unsigned long long u64;
typedef __attribute__((ext_vector_type(8))) short bf16x8;
typedef __attribute__((ext_vector_type(4))) float f32x4;

#define B_   8
#define C_   256
#define HW_  4096
#define N_   32768
#define K_   8192
#define D3   768          // 3 bf16 chunks of 256

// ---- ws layout (bytes) ----
#define O_LOSS  0ULL
#define O_E2    256ULL
#define O_ZN2   33024ULL
#define O_IDX   164096ULL
#define O_CNT   295168ULL
#define O_LIST  426240ULL
#define O_ZT    2523392ULL
#define O_AP    36077824ULL
#define O_BP    86409472ULL
#define O_CAND  98992384ULL
#define WS_NEED 166101248ULL

#define THRESH_T 9e-5f
#define PACK_INF 0x7f80000000000000ULL

// RNE float -> bf16 bits (manual, deterministic)
__device__ __forceinline__ u16 f2bf(float f) {
    u32 x = __float_as_uint(f);
    u32 r = x + 0x7fffu + ((x >> 16) & 1u);
    return (u16)(r >> 16);
}
__device__ __forceinline__ float bf2f(u16 b) {
    return __uint_as_float(((u32)b) << 16);
}

__device__ __forceinline__ void gload16(const void* g, void* l) {
    __builtin_amdgcn_global_load_lds((const __attribute__((address_space(1))) void*)g,
                                     (__attribute__((address_space(3))) void*)l, 16, 0, 0);
}

// =============== prep_z: zT fp32 + A_prep bf16 (swizzled tiles) ==============
// grid 512 = 8 b * 64 hw-chunks, 256 thr. Two c-halves of 128 through LDS.
__global__ __launch_bounds__(256) void vq_prep_z(const float* __restrict__ z,
                                                 float* __restrict__ zT,
                                                 u16* __restrict__ Ap) {
    __shared__ float zl[128][65];
    const int tid = threadIdx.x;
    const int bb = blockIdx.x >> 6;
    const int hwc = blockIdx.x & 63;
    const int hw0 = hwc * 64;
    const int n0 = bb * HW_ + hw0;
    const int lane = tid & 63, wid = tid >> 6;

    for (int h = 0; h < 2; ++h) {
        __syncthreads();
        // load c in [h*128, h*128+128) for 64 hw
        for (int c0 = 0; c0 < 128; c0 += 4) {
            int c = c0 + (tid >> 6);
            zl[c][tid & 63] = z[((size_t)(bb * C_ + h * 128 + c)) * HW_ + hw0 + (tid & 63)];
        }
        __syncthreads();
        // zT writes: 2 rows per wave-iter; lanes 0-31 rowA, 32-63 rowB
        for (int it = 0; it < 8; ++it) {
            int rp = it * 8 + wid * 2 + (lane >> 5);       // 0..63
            int c4 = (lane & 31) * 4;
            float4 v = { zl[c4][rp], zl[c4 + 1][rp], zl[c4 + 2][rp], zl[c4 + 3][rp] };
            *(float4*)(zT + (size_t)(n0 + rp) * C_ + h * 128 + c4) = v;
        }
        // A_prep: kc with (kc&3)>>1 == h  -> cbase_loc = (kc&1)*64
        const int u = tid & 7;
        for (int kc = 0; kc < 12; ++kc) {
            if (((kc & 3) >> 1) != h) continue;
            const int cb_loc = (kc & 1) * 64 + u * 8;
            const bool second = (kc >= 8);
            for (int rh = 0; rh < 2; ++rh) {
                int rloc = (tid >> 3) + rh * 32;
                int n = n0 + rloc;
                int r = n & 127;
                u16 tmp[8];
                #pragma unroll
                for (int j = 0; j < 8; ++j) {
                    float f = zl[cb_loc + j][rloc];
                    u16 b1 = f2bf(f);
                    if (!second) tmp[j] = b1;
                    else         tmp[j] = f2bf(f - bf2f(b1));
                }
                char* dst = (char*)Ap + ((size_t)((n >> 7) * 12 + kc)) * 16384
                          + r * 128 + ((u * 16) ^ ((r & 7) << 4));
                *(uint4*)dst = *(uint4*)tmp;
            }
        }
    }
}

// =============== prep_cb: B_prep bf16 (swizzled tiles) =======================
// grid 128 blocks, 64 codes each.
__global__ __launch_bounds__(256) void vq_prep_cb(const float* __restrict__ cb,
                                                  u16* __restrict__ Bp) {
    const int tid = threadIdx.x;
    const int k0 = blockIdx.x * 64;
    const int u = tid & 7;
    for (int h = 0; h < 2; ++h) {
        int rloc = (tid >> 3) + h * 32;
        int k = k0 + rloc;
        int r = k & 127;
        for (int kc = 0; kc < 12; ++kc) {
            const int cbase = (kc & 3) * 64 + u * 8;
            const bool second = (kc >= 4 && kc < 8);
            const float* src = cb + (size_t)k * C_ + cbase;
            float4 v0 = *(const float4*)(src);
            float4 v1 = *(const float4*)(src + 4);
            float vals[8] = { v0.x, v0.y, v0.z, v0.w, v1.x, v1.y, v1.z, v1.w };
            u16 tmp[8];
            #pragma unroll
            for (int j = 0; j < 8; ++j) {
                u16 b1 = f2bf(vals[j]);
                if (!second) tmp[j] = b1;
                else         tmp[j] = f2bf(vals[j] - bf2f(b1));
            }
            char* dst = (char*)Bp + ((size_t)((k >> 7) * 12 + kc)) * 16384
                      + r * 128 + ((u * 16) ^ ((r & 7) << 4));
            *(uint4*)dst = *(uint4*)tmp;
        }
    }
}

// =============== zn2 from zT (fp64), wave per row ============================
__global__ __launch_bounds__(256) void vq_zn2_zt(const float* __restrict__ zT,
                                                 float* __restrict__ zn2g) {
    const int lane = threadIdx.x & 63, wid = threadIdx.x >> 6;
    const int row = blockIdx.x * 4 + wid;
    float4 v = *(const float4*)(zT + (size_t)row * C_ + lane * 4);
    double acc = (double)v.x * v.x + (double)v.y * v.y
               + (double)v.z * v.z + (double)v.w * v.w;
    #pragma unroll
    for (int off = 32; off >= 1; off >>= 1) acc += __shfl_xor(acc, off);
    if (lane == 0) zn2g[row] = (float)acc;
}

// =============== e2[k] (fp64) ================================================
__global__ __launch_bounds__(256) void vq_e2_kernel(const float* __restrict__ cb,
                                                    float* __restrict__ e2g) {
    int lane = threadIdx.x & 63;
    int w = threadIdx.x >> 6;
    int k = blockIdx.x * 4 + w;
    const float4 v = *reinterpret_cast<const float4*>(cb + (size_t)k * C_ + lane * 4);
    double acc = (double)v.x * v.x + (double)v.y * v.y
               + (double)v.z * v.z + (double)v.w * v.w;
    #pragma unroll
    for (int off = 32; off >= 1; off >>= 1) acc += __shfl_xor(acc, off);
    if (lane == 0) e2g[k] = (float)acc;
}

// =============== main bf16 MFMA scorer: top-2 per (row, 64-codes) ============
// block = 128 codes x 128 rows, K=768. 4 waves in 2x2 (wm=code half, wn=row half).
__global__ __launch_bounds__(256) void vq_gemm_top2(const u16* __restrict__ Ap,
                                                    const u16* __restrict__ Bp,
                                                    u64* __restrict__ cand) {
    __shared__ char lds[32768];          // [0:16K) codes chunk, [16K:32K) z chunk
    const int tid = threadIdx.x;
    const int lane = tid & 63, wid = tid >> 6;
    const int wm = wid >> 1, wn = wid & 1;
    const int l15 = lane & 15, l4 = lane >> 4;

    int raw = blockIdx.x;
    int swz = (raw & 7) * 2048 + (raw >> 3);        // XCD-chunked, bijective
    const int m_tile = swz >> 6;                    // z-row tile 0..255
    const int n_tile = swz & 63;                    // code tile  0..63

    f32x4 acc[4][4];
    #pragma unroll
    for (int i = 0; i < 4; ++i)
        #pragma unroll
        for (int j = 0; j < 4; ++j) acc[i][j] = (f32x4){0.f, 0.f, 0.f, 0.f};

    // per-thread frag read offsets
    int rc[4], rz[4], xc[4], xz[4];
    #pragma unroll
    for (int f = 0; f < 4; ++f) {
        rc[f] = wm * 64 + f * 16 + l15;
        rz[f] = wn * 64 + f * 16 + l15;
        xc[f] = (rc[f] & 7) << 4;
        xz[f] = (rz[f] & 7) << 4;
    }
    const int ob = l4 * 16;

    const char* codes_src = (const char*)Bp + (size_t)(n_tile * 12) * 16384;
    const char* z_src     = (const char*)Ap + (size_t)(m_tile * 12) * 16384;

    for (int kc = 0; kc < 12; ++kc) {
        __syncthreads();
        const char* cs = codes_src + (size_t)kc * 16384;
        const char* zs = z_src + (size_t)kc * 16384;
        #pragma unroll
        for (int i = 0; i < 4; ++i)
            gload16(cs + i * 4096 + tid * 16, lds + i * 4096 + tid * 16);
        #pragma unroll
        for (int i = 0; i < 4; ++i)
            gload16(zs + i * 4096 + tid * 16, lds + 16384 + i * 4096 + tid * 16);
        __syncthreads();
        #pragma unroll
        for (int ks = 0; ks < 2; ++ks) {
            bf16x8 la[4], lb[4];
            #pragma unroll
            for (int f = 0; f < 4; ++f) {
                la[f] = *(const bf16x8*)(lds + rc[f] * 128 + ((ks * 64 + ob) ^ xc[f]));
                lb[f] = *(const bf16x8*)(lds + 16384 + rz[f] * 128 + ((ks * 64 + ob) ^ xz[f]));
            }
            #pragma unroll
            for (int fm = 0; fm < 4; ++fm)
                #pragma unroll
                for (int fn = 0; fn < 4; ++fn)
                    acc[fm][fn] = __builtin_amdgcn_mfma_f32_16x16x32_bf16(
                        la[fm], lb[fn], acc[fm][fn], 0, 0, 0);
        }
    }

    // epilogue: per row (l15 within fn), top-2 over this wave's 64 codes
    const int ktile = n_tile * 2 + wm;
    #pragma unroll
    for (int fn = 0; fn < 4; ++fn) {
        u64 m1 = PACK_INF, m2 = PACK_INF;
        #pragma unroll
        for (int fm = 0; fm < 4; ++fm) {
            #pragma unroll
            for (int rv = 0; rv < 4; ++rv) {
                float s = acc[fm][fn][rv];
                float v = fmaf(-2.f, s, 4.f);
                u32 kk = (u32)(n_tile * 128 + wm * 64 + fm * 16 + l4 * 4 + rv);
                u64 uu = (((u64)__float_as_uint(v)) << 32) | kk;
                if (uu < m1) { m2 = m1; m1 = uu; }
                else if (uu < m2) { m2 = uu; }
            }
        }
        #pragma unroll
        for (int off = 16; off <= 32; off <<= 1) {
            u64 b1 = __shfl_xor(m1, off);
            u64 b2 = __shfl_xor(m2, off);
            u64 lo = m1 < b1 ? m1 : b1;
            u64 hi = m1 < b1 ? b1 : m1;
            u64 s2 = m2 < b2 ? m2 : b2;
            m1 = lo;
            m2 = s2 < hi ? s2 : hi;
        }
        if (l4 == 0) {
            int rowg = m_tile * 128 + wn * 64 + fn * 16 + l15;
            u64* dst = cand + ((size_t)rowg * 128 + ktile) * 2;
            dst[0] = m1; dst[1] = m2;
        }
    }
}

// =============== reduce: global min + candidate list =========================
__global__ __launch_bounds__(256) void vq_reduce(const u64* __restrict__ cand,
                                                 int* __restrict__ cntg,
                                                 int* __restrict__ listg) {
    __shared__ int scnt[4];
    const int lane = threadIdx.x & 63, wid = threadIdx.x >> 6;
    const int row = blockIdx.x * 4 + wid;
    if (lane == 0) scnt[wid] = 0;
    __syncthreads();
    const u64* p = cand + (size_t)row * 256;
    u64 e0 = p[lane * 4 + 0], e1 = p[lane * 4 + 1];
    u64 e2 = p[lane * 4 + 2], e3 = p[lane * 4 + 3];
    u64 m = e0 < e1 ? e0 : e1;
    u64 m23 = e2 < e3 ? e2 : e3;
    m = m < m23 ? m : m23;
    #pragma unroll
    for (int off = 32; off >= 1; off >>= 1) {
        u64 o = __shfl_xor(m, off);
        m = o < m ? o : m;
    }
    float thr = __uint_as_float((u32)(m >> 32)) + THRESH_T;
    u64 ee[4] = { e0, e1, e2, e3 };
    #pragma unroll
    for (int j = 0; j < 4; ++j) {
        float f = __uint_as_float((u32)(ee[j] >> 32));
        if (f <= thr) {
            int slot = atomicAdd(&scnt[wid], 1);
            if (slot < 16) listg[row * 16 + slot] = (int)(ee[j] & 0x3fffu);
        }
    }
    __syncthreads();
    if (lane == 0) {
        int c = scnt[wid];
        cntg[row] = c < 16 ? c : 16;
    }
}

// =============== rescue: exact fp64 distances for candidates =================
__global__ __launch_bounds__(256) void vq_rescue(const float* __restrict__ zT,
                                                 const float* __restrict__ cb,
                                                 const float* __restrict__ e2g,
                                                 const float* __restrict__ zn2g,
                                                 const int* __restrict__ cntg,
                                                 const int* __restrict__ listg,
                                                 int* __restrict__ idxg) {
    const int lane = threadIdx.x & 63, wid = threadIdx.x >> 6;
    const int row = blockIdx.x * 4 + wid;
    const float4 zv = *(const float4*)(zT + (size_t)row * C_ + lane * 4);
    const float zn2a = zn2g[row];
    const int cnt = cntg[row];
    float bd = INFINITY;
    int bk = 0x7fffffff;
    for (int j = 0; j < cnt; ++j) {
        int k = listg[row * 16 + j];
        const float4 cv = *(const float4*)(cb + (size_t)k * C_ + lane * 4);
        double s = (double)zv.x * cv.x + (double)zv.y * cv.y
                 + (double)zv.z * cv.z + (double)zv.w * cv.w;
        #pragma unroll
        for (int off = 32; off >= 1; off >>= 1) s += __shfl_xor(s, off);
        float sf = (float)s;
        float d = (zn2a + e2g[k]) - 2.0f * sf;
        if (d < bd || (d == bd && k < bk)) { bd = d; bk = k; }
    }
    if (lane == 0) idxg[row] = bk;
}

// =============== z_q (STE mimic) + loss ======================================
__global__ __launch_bounds__(256) void vq_zq_loss_kernel(const float* __restrict__ z,
                                                         const float* __restrict__ cb,
                                                         const int* __restrict__ idxg,
                                                         float* __restrict__ out,
                                                         double* __restrict__ loss_sum) {
    const size_t i = (size_t)blockIdx.x * 256 + threadIdx.x;
    const int hw = (int)(i & 4095);
    const int bc = (int)(i >> 12);
    const int c = bc & 255;
    const int b = bc >> 8;
    const int n = (b << 12) + hw;
    const float zv = z[i];
    const int k = idxg[n];
    const float cv = cb[(size_t)k * C_ + c];
    const float t = cv - zv;
    out[i] = zv + t;
    double sq = (double)t * (double)t;
    #pragma unroll
    for (int off = 32; off >= 1; off >>= 1) sq += __shfl_xor(sq, off);
    __shared__ double ls[4];
    const int lane = threadIdx.x & 63, wid = threadIdx.x >> 6;
    if (lane == 0) ls[wid] = sq;
    __syncthreads();
    if (threadIdx.x == 0) atomicAdd(loss_sum, ls[0] + ls[1] + ls[2] + ls[3]);
}

__global__ __launch_bounds__(256) void vq_final_kernel(const int* __restrict__ idxg,
                                                       const double* __restrict__ loss_sum,
                                                       float* __restrict__ out) {
    const int i = blockIdx.x * 256 + threadIdx.x;
    out[8388609 + i] = (float)idxg[i];
    if (i == 0) out[8388608] = (float)(1.25 * (*loss_sum) / 8388608.0);
}

// =============== fallback fp64 path (round-1, used if ws too small) ==========
__global__ __launch_bounds__(256) void vq_zn2_old(const float* __restrict__ z,
                                                  float* __restrict__ zn2g) {
    int n = blockIdx.x * 256 + threadIdx.x;
    int b = n >> 12;
    int hw = n & 4095;
    const float* p = z + (size_t)b * C_ * HW_ + hw;
    double acc = 0.0;
    #pragma unroll 8
    for (int c = 0; c < C_; ++c) {
        float v = p[(size_t)c * HW_];
        acc += (double)v * (double)v;
    }
    zn2g[n] = (float)acc;
}

__global__ __launch_bounds__(256) void vq_argmin_old(const float* __restrict__ z,
                                                     const float* __restrict__ cb,
                                                     const float* __restrict__ e2g,
                                                     const float* __restrict__ zn2g,
                                                     int* __restrict__ idxg) {
    __shared__ float zt[C_][32];
    __shared__ float et[64][64];
    const int tid = threadIdx.x;
    const int n0 = blockIdx.x * 32;
    const int b = n0 >> 12;
    const int hw0 = n0 & 4095;
    {
        const int nn = tid & 31;
        const int c8 = tid >> 5;
        #pragma unroll
        for (int j = 0; j < 32; ++j) {
            const int c = j * 8 + c8;
            zt[c][nn] = z[(size_t)(b * C_ + c) * HW_ + hw0 + nn];
        }
    }
    const int cg = tid & 15;
    const int rg = tid >> 4;
    const int r0 = rg * 2;
    __syncthreads();
    const float zn2a = zn2g[n0 + r0];
    const float zn2b = zn2g[n0 + r0 + 1];
    float dmin0 = INFINITY, dmin1 = INFINITY;
    int imin0 = 0, imin1 = 0;
    const int kk = tid >> 2;
    const int c4 = (tid & 3) * 16;
    for (int kt = 0; kt < K_; kt += 64) {
        double s00 = 0, s01 = 0, s02 = 0, s03 = 0;
        double s10 = 0, s11 = 0, s12 = 0, s13 = 0;
        for (int cc = 0; cc < C_; cc += 64) {
            __syncthreads();
            {
                const float* src = cb + (size_t)(kt + kk) * C_ + cc + c4;
                #pragma unroll
                for (int j = 0; j < 16; j += 4) {
                    const float4 v = *reinterpret_cast<const float4*>(src + j);
                    et[c4 + j + 0][kk] = v.x;
                    et[c4 + j + 1][kk] = v.y;
                    et[c4 + j + 2][kk] = v.z;
                    et[c4 + j + 3][kk] = v.w;
                }
            }
            __syncthreads();
            #pragma unroll 4
            for (int c2 = 0; c2 < 64; ++c2) {
                const float2 zv = *reinterpret_cast<const float2*>(&zt[cc + c2][r0]);
                const float4 ev = *reinterpret_cast<const float4*>(&et[c2][cg * 4]);
                const double z0 = (double)zv.x, z1 = (double)zv.y;
                s00 += z0 * ev.x; s01 += z0 * ev.y; s02 += z0 * ev.z; s03 += z0 * ev.w;
                s10 += z1 * ev.x; s11 += z1 * ev.y; s12 += z1 * ev.z; s13 += z1 * ev.w;
            }
        }
        const int kbase = kt + cg * 4;
        const float sf0[4] = {(float)s00, (float)s01, (float)s02, (float)s03};
        const float sf1[4] = {(float)s10, (float)s11, (float)s12, (float)s13};
        #pragma unroll
        for (int j = 0; j < 4; ++j) {
            const int k = kbase + j;
            const float e2k = e2g[k];
            const float d0 = (zn2a + e2k) - 2.0f * sf0[j];
            const float d1 = (zn2b + e2k) - 2.0f * sf1[j];
            if (d0 < dmin0) { dmin0 = d0; imin0 = k; }
            if (d1 < dmin1) { dmin1 = d1; imin1 = k; }
        }
    }
    #pragma unroll
    for (int off = 8; off >= 1; off >>= 1) {
        const float od0 = __shfl_xor(dmin0, off);
        const int   oi0 = __shfl_xor(imin0, off);
        const float od1 = __shfl_xor(dmin1, off);
        const int   oi1 = __shfl_xor(imin1, off);
        if (od0 < dmin0 || (od0 == dmin0 && oi0 < imin0)) { dmin0 = od0; imin0 = oi0; }
        if (od1 < dmin1 || (od1 == dmin1 && oi1 < imin1)) { dmin1 = od1; imin1 = oi1; }
    }
    if (cg == 0) {
        idxg[n0 + r0]     = imin0;
        idxg[n0 + r0 + 1] = imin1;
    }
}

extern "C" void kernel_launch(void* const* d_in, const int* in_sizes, int n_in,
                              void* d_out, int out_size, void* d_ws, size_t ws_size,
                              hipStream_t stream) {
    const float* z  = (const float*)d_in[0];
    const float* cb = (const float*)d_in[1];
    float* out = (float*)d_out;
    char* ws = (char*)d_ws;

    double* loss_sum = (double*)(ws + O_LOSS);
    float*  e2g  = (float*)(ws + O_E2);
    float*  zn2g = (float*)(ws + O_ZN2);
    int*    idxg = (int*)(ws + O_IDX);

    hipMemsetAsync(loss_sum, 0, sizeof(double), stream);
    hipLaunchKernelGGL(vq_e2_kernel, dim3(K_ / 4), dim3(256), 0, stream, cb, e2g);

    if (ws_size >= WS_NEED) {
        int*   cntg  = (int*)(ws + O_CNT);
        int*   listg = (int*)(ws + O_LIST);
        float* zT    = (float*)(ws + O_ZT);
        u16*   Ap    = (u16*)(ws + O_AP);
        u16*   Bp    = (u16*)(ws + O_BP);
        u64*   cand  = (u64*)(ws + O_CAND);

        hipLaunchKernelGGL(vq_prep_z, dim3(512), dim3(256), 0, stream, z, zT, Ap);
        hipLaunchKernelGGL(vq_prep_cb, dim3(128), dim3(256), 0, stream, cb, Bp);
        hipLaunchKernelGGL(vq_zn2_zt, dim3(N_ / 4), dim3(256), 0, stream, zT, zn2g);
        hipLaunchKernelGGL(vq_gemm_top2, dim3(16384), dim3(256), 0, stream, Ap, Bp, cand);
        hipLaunchKernelGGL(vq_reduce, dim3(N_ / 4), dim3(256), 0, stream, cand, cntg, listg);
        hipLaunchKernelGGL(vq_rescue, dim3(N_ / 4), dim3(256), 0, stream,
                           zT, cb, e2g, zn2g, cntg, listg, idxg);
    } else {
        hipLaunchKernelGGL(vq_zn2_old, dim3(N_ / 256), dim3(256), 0, stream, z, zn2g);
        hipLaunchKernelGGL(vq_argmin_old, dim3(N_ / 32), dim3(256), 0, stream,
                           z, cb, e2g, zn2g, idxg);
    }

    hipLaunchKernelGGL(vq_zq_loss_kernel, dim3((B_ * C_ * HW_) / 256), dim3(256), 0, stream,
                       z, cb, idxg, out, loss_sum);
    hipLaunchKernelGGL(vq_final_kernel, dim3(N_ / 256), dim3(256), 0, stream,
                       idxg, loss_sum, out);
}

// Round 3
// 292.118 us; speedup vs baseline: 16.5332x; 3.4758x over previous
//
#include <hip/hip_runtime.h>
#include <hip/hip_bf16.h>
#include <math.h>

typedef unsigned short u16;
typedef unsigned int u32;
typedef unsigned long long u64;
typedef __attribute__((ext_vector_type(8))) _Float16 f16x8;
typedef __attribute__((ext_vector_type(4))) float f32x4;

#define B_   8
#define C_   256
#define HW_  4096
#define N_   32768
#define K_   8192

// ---- ws layout (bytes) ----
#define O_LOSSP 0ULL            // 2048 doubles
#define O_E2    16384ULL        // 8192 f32
#define O_ZN2   49152ULL        // 32768 f32
#define O_IDX   180224ULL       // 32768 i32
#define O_CNT   311296ULL       // 32768 i32
#define O_LIST  442368ULL       // 32768*16 i32
#define O_ZT    2539520ULL      // 32768*256 f32
#define O_AP    36093952ULL     // 256 tiles * 4 kc * 16KB (f16)
#define O_BP    52871168ULL     // 64 tiles * 4 kc * 16KB (f16)
#define O_CAND  57065472ULL     // 32768*128*2 u64
#define WS_NEED 124174336ULL

#define THRESH_T 9e-5f
#define PACK_INF 0x7f80000000000000ULL

__device__ __forceinline__ u16 f2h(float f) {
    _Float16 h = (_Float16)f;                 // v_cvt_f16_f32, RNE, deterministic
    return __builtin_bit_cast(u16, h);
}

__device__ __forceinline__ void gload16(const void* g, void* l) {
    __builtin_amdgcn_global_load_lds((const __attribute__((address_space(1))) void*)g,
                                     (__attribute__((address_space(3))) void*)l, 16, 0, 0);
}

// =============== prep_z: zT fp32 + A_prep f16 (swizzled tiles) ===============
// grid 512 = 8 b * 64 hw-chunks, 256 thr.
__global__ __launch_bounds__(256) void vq_prep_z(const float* __restrict__ z,
                                                 float* __restrict__ zT,
                                                 u16* __restrict__ Ap) {
    __shared__ float zl[128][65];
    const int tid = threadIdx.x;
    const int bb = blockIdx.x >> 6;
    const int hwc = blockIdx.x & 63;
    const int hw0 = hwc * 64;
    const int n0 = bb * HW_ + hw0;
    const int lane = tid & 63, wid = tid >> 6;
    const int u = tid & 7;

    for (int h = 0; h < 2; ++h) {
        __syncthreads();
        for (int c0 = 0; c0 < 128; c0 += 4) {
            int c = c0 + (tid >> 6);
            zl[c][tid & 63] = z[((size_t)(bb * C_ + h * 128 + c)) * HW_ + hw0 + (tid & 63)];
        }
        __syncthreads();
        // zT: transpose out
        for (int it = 0; it < 8; ++it) {
            int rp = it * 8 + wid * 2 + (lane >> 5);
            int c4 = (lane & 31) * 4;
            float4 v = { zl[c4][rp], zl[c4 + 1][rp], zl[c4 + 2][rp], zl[c4 + 3][rp] };
            *(float4*)(zT + (size_t)(n0 + rp) * C_ + h * 128 + c4) = v;
        }
        // Ap: kc = h*2 + q, chunk-local c = q*64 + u*8
        #pragma unroll
        for (int q = 0; q < 2; ++q) {
            const int kc = h * 2 + q;
            #pragma unroll
            for (int rh = 0; rh < 2; ++rh) {
                int rloc = (tid >> 3) + rh * 32;
                int n = n0 + rloc;
                int r = n & 127;
                u16 tmp[8];
                #pragma unroll
                for (int j = 0; j < 8; ++j)
                    tmp[j] = f2h(zl[q * 64 + u * 8 + j][rloc]);
                char* dst = (char*)Ap + ((size_t)((n >> 7) * 4 + kc)) * 16384
                          + r * 128 + ((u * 16) ^ ((r & 7) << 4));
                *(uint4*)dst = *(uint4*)tmp;
            }
        }
    }
}

// =============== prep_cb: B_prep f16, e scaled by 2^13 =======================
// grid 128 blocks, 64 codes each.
__global__ __launch_bounds__(256) void vq_prep_cb(const float* __restrict__ cb,
                                                  u16* __restrict__ Bp) {
    const int tid = threadIdx.x;
    const int k0 = blockIdx.x * 64;
    const int u = tid & 7;
    for (int h = 0; h < 2; ++h) {
        int rloc = (tid >> 3) + h * 32;
        int k = k0 + rloc;
        int r = k & 127;
        #pragma unroll
        for (int kc = 0; kc < 4; ++kc) {
            const float* src = cb + (size_t)k * C_ + kc * 64 + u * 8;
            float4 v0 = *(const float4*)(src);
            float4 v1 = *(const float4*)(src + 4);
            float vals[8] = { v0.x, v0.y, v0.z, v0.w, v1.x, v1.y, v1.z, v1.w };
            u16 tmp[8];
            #pragma unroll
            for (int j = 0; j < 8; ++j)
                tmp[j] = f2h(vals[j] * 8192.0f);   // exact pow2 scale, then RNE
            char* dst = (char*)Bp + ((size_t)((k >> 7) * 4 + kc)) * 16384
                      + r * 128 + ((u * 16) ^ ((r & 7) << 4));
            *(uint4*)dst = *(uint4*)tmp;
        }
    }
}

// =============== zn2 from zT (fp64) ==========================================
__global__ __launch_bounds__(256) void vq_zn2_zt(const float* __restrict__ zT,
                                                 float* __restrict__ zn2g) {
    const int lane = threadIdx.x & 63, wid = threadIdx.x >> 6;
    const int row = blockIdx.x * 4 + wid;
    float4 v = *(const float4*)(zT + (size_t)row * C_ + lane * 4);
    double acc = (double)v.x * v.x + (double)v.y * v.y
               + (double)v.z * v.z + (double)v.w * v.w;
    #pragma unroll
    for (int off = 32; off >= 1; off >>= 1) acc += __shfl_xor(acc, off);
    if (lane == 0) zn2g[row] = (float)acc;
}

// =============== e2[k] (fp64) ================================================
__global__ __launch_bounds__(256) void vq_e2_kernel(const float* __restrict__ cb,
                                                    float* __restrict__ e2g) {
    int lane = threadIdx.x & 63;
    int w = threadIdx.x >> 6;
    int k = blockIdx.x * 4 + w;
    const float4 v = *reinterpret_cast<const float4*>(cb + (size_t)k * C_ + lane * 4);
    double acc = (double)v.x * v.x + (double)v.y * v.y
               + (double)v.z * v.z + (double)v.w * v.w;
    #pragma unroll
    for (int off = 32; off >= 1; off >>= 1) acc += __shfl_xor(acc, off);
    if (lane == 0) e2g[k] = (float)acc;
}

// =============== main f16 MFMA scorer: top-2 per (row, 64-codes) =============
// 128 codes x 128 rows per block, K=256 (4 chunks of 64), double-buffered LDS.
__global__ __launch_bounds__(256) void vq_gemm_top2(const u16* __restrict__ Ap,
                                                    const u16* __restrict__ Bp,
                                                    u64* __restrict__ cand) {
    __shared__ char lds[65536];          // 2 bufs x {codes 16K, z 16K}
    const int tid = threadIdx.x;
    const int lane = tid & 63, wid = tid >> 6;
    const int wm = wid >> 1, wn = wid & 1;
    const int l15 = lane & 15, l4 = lane >> 4;

    // L2-aware order: XCD owns 8 n_tiles (Bp slice 512 KB, L2-resident);
    // 8 consecutive blocks share one Ap m-tile.
    const int raw = blockIdx.x;
    const int m_tile = raw >> 6;                       // 0..255
    const int n_tile = (raw & 7) * 8 + ((raw >> 3) & 7); // 0..63

    f32x4 acc[4][4];
    #pragma unroll
    for (int i = 0; i < 4; ++i)
        #pragma unroll
        for (int j = 0; j < 4; ++j) acc[i][j] = (f32x4){0.f, 0.f, 0.f, 0.f};

    int rc[4], rz[4], xc[4], xz[4];
    #pragma unroll
    for (int f = 0; f < 4; ++f) {
        rc[f] = wm * 64 + f * 16 + l15;
        rz[f] = wn * 64 + f * 16 + l15;
        xc[f] = (rc[f] & 7) << 4;
        xz[f] = (rz[f] & 7) << 4;
    }
    const int ob = l4 * 16;

    const char* codes_src = (const char*)Bp + (size_t)(n_tile * 4) * 16384;
    const char* z_src     = (const char*)Ap + (size_t)(m_tile * 4) * 16384;

    #define STAGE(buf, kc)                                                        \
        do {                                                                      \
            const char* cs_ = codes_src + (size_t)(kc) * 16384;                   \
            const char* zs_ = z_src + (size_t)(kc) * 16384;                       \
            char* lb_ = lds + (buf) * 32768;                                      \
            _Pragma("unroll")                                                     \
            for (int i_ = 0; i_ < 4; ++i_)                                        \
                gload16(cs_ + i_ * 4096 + tid * 16, lb_ + i_ * 4096 + tid * 16);  \
            _Pragma("unroll")                                                     \
            for (int i_ = 0; i_ < 4; ++i_)                                        \
                gload16(zs_ + i_ * 4096 + tid * 16,                               \
                        lb_ + 16384 + i_ * 4096 + tid * 16);                      \
        } while (0)

    STAGE(0, 0);
    __syncthreads();

    for (int kc = 0; kc < 4; ++kc) {
        const int cur = kc & 1;
        if (kc < 3) STAGE(cur ^ 1, kc + 1);
        const char* base = lds + cur * 32768;
        #pragma unroll
        for (int ks = 0; ks < 2; ++ks) {
            f16x8 la[4], lb[4];
            #pragma unroll
            for (int f = 0; f < 4; ++f) {
                la[f] = *(const f16x8*)(base + rc[f] * 128 + ((ks * 64 + ob) ^ xc[f]));
                lb[f] = *(const f16x8*)(base + 16384 + rz[f] * 128 + ((ks * 64 + ob) ^ xz[f]));
            }
            #pragma unroll
            for (int fm = 0; fm < 4; ++fm)
                #pragma unroll
                for (int fn = 0; fn < 4; ++fn)
                    acc[fm][fn] = __builtin_amdgcn_mfma_f32_16x16x32_f16(
                        la[fm], lb[fn], acc[fm][fn], 0, 0, 0);
        }
        __syncthreads();   // drains vmcnt for next buf; protects cur for overwrite
    }
    #undef STAGE

    // epilogue: v = 4 - 2*s_true = fma(s_scaled, -2^-12, 4)
    const int ktile = n_tile * 2 + wm;
    #pragma unroll
    for (int fn = 0; fn < 4; ++fn) {
        u64 m1 = PACK_INF, m2 = PACK_INF;
        #pragma unroll
        for (int fm = 0; fm < 4; ++fm) {
            #pragma unroll
            for (int rv = 0; rv < 4; ++rv) {
                float v = fmaf(acc[fm][fn][rv], -0x1p-12f, 4.0f);
                u32 kk = (u32)(n_tile * 128 + wm * 64 + fm * 16 + l4 * 4 + rv);
                u64 uu = (((u64)__float_as_uint(v)) << 32) | kk;
                if (uu < m1) { m2 = m1; m1 = uu; }
                else if (uu < m2) { m2 = uu; }
            }
        }
        #pragma unroll
        for (int off = 16; off <= 32; off <<= 1) {
            u64 b1 = __shfl_xor(m1, off);
            u64 b2 = __shfl_xor(m2, off);
            u64 lo = m1 < b1 ? m1 : b1;
            u64 hi = m1 < b1 ? b1 : m1;
            u64 s2 = m2 < b2 ? m2 : b2;
            m1 = lo;
            m2 = s2 < hi ? s2 : hi;
        }
        if (l4 == 0) {
            int rowg = m_tile * 128 + wn * 64 + fn * 16 + l15;
            u64* dst = cand + ((size_t)rowg * 128 + ktile) * 2;
            dst[0] = m1; dst[1] = m2;
        }
    }
}

// =============== reduce: global min + candidate list =========================
__global__ __launch_bounds__(256) void vq_reduce(const u64* __restrict__ cand,
                                                 int* __restrict__ cntg,
                                                 int* __restrict__ listg) {
    __shared__ int scnt[4];
    const int lane = threadIdx.x & 63, wid = threadIdx.x >> 6;
    const int row = blockIdx.x * 4 + wid;
    if (lane == 0) scnt[wid] = 0;
    __syncthreads();
    const u64* p = cand + (size_t)row * 256;
    u64 e0 = p[lane * 4 + 0], e1 = p[lane * 4 + 1];
    u64 e2 = p[lane * 4 + 2], e3 = p[lane * 4 + 3];
    u64 m = e0 < e1 ? e0 : e1;
    u64 m23 = e2 < e3 ? e2 : e3;
    m = m < m23 ? m : m23;
    #pragma unroll
    for (int off = 32; off >= 1; off >>= 1) {
        u64 o = __shfl_xor(m, off);
        m = o < m ? o : m;
    }
    float thr = __uint_as_float((u32)(m >> 32)) + THRESH_T;
    u64 ee[4] = { e0, e1, e2, e3 };
    #pragma unroll
    for (int j = 0; j < 4; ++j) {
        float f = __uint_as_float((u32)(ee[j] >> 32));
        if (f <= thr) {
            int slot = atomicAdd(&scnt[wid], 1);
            if (slot < 16) listg[row * 16 + slot] = (int)(ee[j] & 0x3fffu);
        }
    }
    __syncthreads();
    if (lane == 0) {
        int c = scnt[wid];
        cntg[row] = c < 16 ? c : 16;
    }
}

// =============== rescue: exact fp64 distances (round-1 arithmetic) ===========
__global__ __launch_bounds__(256) void vq_rescue(const float* __restrict__ zT,
                                                 const float* __restrict__ cb,
                                                 const float* __restrict__ e2g,
                                                 const float* __restrict__ zn2g,
                                                 const int* __restrict__ cntg,
                                                 const int* __restrict__ listg,
                                                 int* __restrict__ idxg) {
    const int lane = threadIdx.x & 63, wid = threadIdx.x >> 6;
    const int row = blockIdx.x * 4 + wid;
    const float4 zv = *(const float4*)(zT + (size_t)row * C_ + lane * 4);
    const float zn2a = zn2g[row];
    const int cnt = cntg[row];
    float bd = INFINITY;
    int bk = 0x7fffffff;
    for (int j = 0; j < cnt; ++j) {
        int k = listg[row * 16 + j];
        const float4 cv = *(const float4*)(cb + (size_t)k * C_ + lane * 4);
        double s = (double)zv.x * cv.x + (double)zv.y * cv.y
                 + (double)zv.z * cv.z + (double)zv.w * cv.w;
        #pragma unroll
        for (int off = 32; off >= 1; off >>= 1) s += __shfl_xor(s, off);
        float sf = (float)s;
        float d = (zn2a + e2g[k]) - 2.0f * sf;
        if (d < bd || (d == bd && k < bk)) { bd = d; bk = k; }
    }
    if (lane == 0) idxg[row] = bk;
}

// =============== z_q (STE mimic) + per-block loss partials ===================
__global__ __launch_bounds__(256) void vq_zq_loss_kernel(const float* __restrict__ z,
                                                         const float* __restrict__ cb,
                                                         const int* __restrict__ idxg,
                                                         float* __restrict__ out,
                                                         double* __restrict__ partial) {
    double acc = 0.0;
    for (size_t i = (size_t)blockIdx.x * 256 + threadIdx.x; i < 8388608ULL;
         i += 2048ULL * 256ULL) {
        const int hw = (int)(i & 4095);
        const int bc = (int)(i >> 12);
        const int c = bc & 255;
        const int b = bc >> 8;
        const int n = (b << 12) + hw;
        const float zv = z[i];
        const int k = idxg[n];
        const float cv = cb[(size_t)k * C_ + c];
        const float t = cv - zv;
        out[i] = zv + t;
        acc += (double)t * (double)t;
    }
    #pragma unroll
    for (int off = 32; off >= 1; off >>= 1) acc += __shfl_xor(acc, off);
    __shared__ double ls[4];
    const int lane = threadIdx.x & 63, wid = threadIdx.x >> 6;
    if (lane == 0) ls[wid] = acc;
    __syncthreads();
    if (threadIdx.x == 0) partial[blockIdx.x] = ls[0] + ls[1] + ls[2] + ls[3];
}

// =============== loss finalize (1 block) =====================================
__global__ __launch_bounds__(256) void vq_loss_final(const double* __restrict__ partial,
                                                     float* __restrict__ out) {
    double acc = 0.0;
    for (int j = threadIdx.x; j < 2048; j += 256) acc += partial[j];
    #pragma unroll
    for (int off = 32; off >= 1; off >>= 1) acc += __shfl_xor(acc, off);
    __shared__ double ls[4];
    const int lane = threadIdx.x & 63, wid = threadIdx.x >> 6;
    if (lane == 0) ls[wid] = acc;
    __syncthreads();
    if (threadIdx.x == 0)
        out[8388608] = (float)(1.25 * (ls[0] + ls[1] + ls[2] + ls[3]) / 8388608.0);
}

// =============== indices as float ============================================
__global__ __launch_bounds__(256) void vq_final_kernel(const int* __restrict__ idxg,
                                                       float* __restrict__ out) {
    const int i = blockIdx.x * 256 + threadIdx.x;
    out[8388609 + i] = (float)idxg[i];
}

// =============== fallback fp64 path (round-1) ================================
__global__ __launch_bounds__(256) void vq_zn2_old(const float* __restrict__ z,
                                                  float* __restrict__ zn2g) {
    int n = blockIdx.x * 256 + threadIdx.x;
    int b = n >> 12;
    int hw = n & 4095;
    const float* p = z + (size_t)b * C_ * HW_ + hw;
    double acc = 0.0;
    #pragma unroll 8
    for (int c = 0; c < C_; ++c) {
        float v = p[(size_t)c * HW_];
        acc += (double)v * (double)v;
    }
    zn2g[n] = (float)acc;
}

__global__ __launch_bounds__(256) void vq_argmin_old(const float* __restrict__ z,
                                                     const float* __restrict__ cb,
                                                     const float* __restrict__ e2g,
                                                     const float* __restrict__ zn2g,
                                                     int* __restrict__ idxg) {
    __shared__ float zt[C_][32];
    __shared__ float et[64][64];
    const int tid = threadIdx.x;
    const int n0 = blockIdx.x * 32;
    const int b = n0 >> 12;
    const int hw0 = n0 & 4095;
    {
        const int nn = tid & 31;
        const int c8 = tid >> 5;
        #pragma unroll
        for (int j = 0; j < 32; ++j) {
            const int c = j * 8 + c8;
            zt[c][nn] = z[(size_t)(b * C_ + c) * HW_ + hw0 + nn];
        }
    }
    const int cg = tid & 15;
    const int rg = tid >> 4;
    const int r0 = rg * 2;
    __syncthreads();
    const float zn2a = zn2g[n0 + r0];
    const float zn2b = zn2g[n0 + r0 + 1];
    float dmin0 = INFINITY, dmin1 = INFINITY;
    int imin0 = 0, imin1 = 0;
    const int kk = tid >> 2;
    const int c4 = (tid & 3) * 16;
    for (int kt = 0; kt < K_; kt += 64) {
        double s00 = 0, s01 = 0, s02 = 0, s03 = 0;
        double s10 = 0, s11 = 0, s12 = 0, s13 = 0;
        for (int cc = 0; cc < C_; cc += 64) {
            __syncthreads();
            {
                const float* src = cb + (size_t)(kt + kk) * C_ + cc + c4;
                #pragma unroll
                for (int j = 0; j < 16; j += 4) {
                    const float4 v = *reinterpret_cast<const float4*>(src + j);
                    et[c4 + j + 0][kk] = v.x;
                    et[c4 + j + 1][kk] = v.y;
                    et[c4 + j + 2][kk] = v.z;
                    et[c4 + j + 3][kk] = v.w;
                }
            }
            __syncthreads();
            #pragma unroll 4
            for (int c2 = 0; c2 < 64; ++c2) {
                const float2 zv = *reinterpret_cast<const float2*>(&zt[cc + c2][r0]);
                const float4 ev = *reinterpret_cast<const float4*>(&et[c2][cg * 4]);
                const double z0 = (double)zv.x, z1 = (double)zv.y;
                s00 += z0 * ev.x; s01 += z0 * ev.y; s02 += z0 * ev.z; s03 += z0 * ev.w;
                s10 += z1 * ev.x; s11 += z1 * ev.y; s12 += z1 * ev.z; s13 += z1 * ev.w;
            }
        }
        const int kbase = kt + cg * 4;
        const float sf0[4] = {(float)s00, (float)s01, (float)s02, (float)s03};
        const float sf1[4] = {(float)s10, (float)s11, (float)s12, (float)s13};
        #pragma unroll
        for (int j = 0; j < 4; ++j) {
            const int k = kbase + j;
            const float e2k = e2g[k];
            const float d0 = (zn2a + e2k) - 2.0f * sf0[j];
            const float d1 = (zn2b + e2k) - 2.0f * sf1[j];
            if (d0 < dmin0) { dmin0 = d0; imin0 = k; }
            if (d1 < dmin1) { dmin1 = d1; imin1 = k; }
        }
    }
    #pragma unroll
    for (int off = 8; off >= 1; off >>= 1) {
        const float od0 = __shfl_xor(dmin0, off);
        const int   oi0 = __shfl_xor(imin0, off);
        const float od1 = __shfl_xor(dmin1, off);
        const int   oi1 = __shfl_xor(imin1, off);
        if (od0 < dmin0 || (od0 == dmin0 && oi0 < imin0)) { dmin0 = od0; imin0 = oi0; }
        if (od1 < dmin1 || (od1 == dmin1 && oi1 < imin1)) { dmin1 = od1; imin1 = oi1; }
    }
    if (cg == 0) {
        idxg[n0 + r0]     = imin0;
        idxg[n0 + r0 + 1] = imin1;
    }
}

extern "C" void kernel_launch(void* const* d_in, const int* in_sizes, int n_in,
                              void* d_out, int out_size, void* d_ws, size_t ws_size,
                              hipStream_t stream) {
    const float* z  = (const float*)d_in[0];
    const float* cb = (const float*)d_in[1];
    float* out = (float*)d_out;
    char* ws = (char*)d_ws;

    double* lossp = (double*)(ws + O_LOSSP);
    float*  e2g  = (float*)(ws + O_E2);
    float*  zn2g = (float*)(ws + O_ZN2);
    int*    idxg = (int*)(ws + O_IDX);

    hipLaunchKernelGGL(vq_e2_kernel, dim3(K_ / 4), dim3(256), 0, stream, cb, e2g);

    if (ws_size >= WS_NEED) {
        int*   cntg  = (int*)(ws + O_CNT);
        int*   listg = (int*)(ws + O_LIST);
        float* zT    = (float*)(ws + O_ZT);
        u16*   Ap    = (u16*)(ws + O_AP);
        u16*   Bp    = (u16*)(ws + O_BP);
        u64*   cand  = (u64*)(ws + O_CAND);

        hipLaunchKernelGGL(vq_prep_z, dim3(512), dim3(256), 0, stream, z, zT, Ap);
        hipLaunchKernelGGL(vq_prep_cb, dim3(128), dim3(256), 0, stream, cb, Bp);
        hipLaunchKernelGGL(vq_zn2_zt, dim3(N_ / 4), dim3(256), 0, stream, zT, zn2g);
        hipLaunchKernelGGL(vq_gemm_top2, dim3(16384), dim3(256), 0, stream, Ap, Bp, cand);
        hipLaunchKernelGGL(vq_reduce, dim3(N_ / 4), dim3(256), 0, stream, cand, cntg, listg);
        hipLaunchKernelGGL(vq_rescue, dim3(N_ / 4), dim3(256), 0, stream,
                           zT, cb, e2g, zn2g, cntg, listg, idxg);
    } else {
        hipLaunchKernelGGL(vq_zn2_old, dim3(N_ / 256), dim3(256), 0, stream, z, zn2g);
        hipLaunchKernelGGL(vq_argmin_old, dim3(N_ / 32), dim3(256), 0, stream,
                           z, cb, e2g, zn2g, idxg);
    }

    hipLaunchKernelGGL(vq_zq_loss_kernel, dim3(2048), dim3(256), 0, stream,
                       z, cb, idxg, out, lossp);
    hipLaunchKernelGGL(vq_loss_final, dim3(1), dim3(256), 0, stream, lossp, out);
    hipLaunchKernelGGL(vq_final_kernel, dim3(N_ / 256), dim3(256), 0, stream, idxg, out);
}

// Round 5
// 244.972 us; speedup vs baseline: 19.7151x; 1.1925x over previous
//
#include <hip/hip_runtime.h>
#include <hip/hip_bf16.h>
#include <math.h>

typedef unsigned short u16;
typedef unsigned int u32;
typedef unsigned long long u64;
typedef __attribute__((ext_vector_type(8))) _Float16 f16x8;
typedef __attribute__((ext_vector_type(4))) float f32x4;

#define B_   8
#define C_   256
#define HW_  4096
#define N_   32768
#define K_   8192

// ---- ws layout (bytes) ----
#define O_LOSSP 0ULL            // 2048 doubles
#define O_E2    16384ULL        // 8192 f32
#define O_ZN2   49152ULL        // 32768 f32
#define O_IDX   180224ULL       // 32768 i32
#define O_ZT    311296ULL       // 32768*256 f32
#define O_AP    33865728ULL     // 256 tiles * 4 kc * 16KB (f16)
#define O_BP    50642944ULL     // 64 tiles * 4 kc * 16KB (f16)
#define O_CAND  54837248ULL     // 32768*128*2 u32
#define WS_NEED 88391680ULL

#define THRESH_T 9e-5f

__device__ __forceinline__ u16 f2h(float f) {
    _Float16 h = (_Float16)f;                 // v_cvt_f16_f32, RNE, deterministic
    return __builtin_bit_cast(u16, h);
}

__device__ __forceinline__ void gload16(const void* g, void* l) {
    __builtin_amdgcn_global_load_lds((const __attribute__((address_space(1))) void*)g,
                                     (__attribute__((address_space(3))) void*)l, 16, 0, 0);
}

// =============== prep_z: zT fp32 + A_prep f16 + zn2 (fused) ==================
// grid 512 = 8 b * 64 hw-chunks, 256 thr.
__global__ __launch_bounds__(256) void vq_prep_z(const float* __restrict__ z,
                                                 float* __restrict__ zT,
                                                 u16* __restrict__ Ap,
                                                 float* __restrict__ zn2g) {
    __shared__ float zl[128][65];
    const int tid = threadIdx.x;
    const int bb = blockIdx.x >> 6;
    const int hwc = blockIdx.x & 63;
    const int hw0 = hwc * 64;
    const int n0 = bb * HW_ + hw0;
    const int lane = tid & 63, wid = tid >> 6;
    const int u = tid & 7;
    double zacc[2] = { 0.0, 0.0 };

    for (int h = 0; h < 2; ++h) {
        __syncthreads();
        for (int c0 = 0; c0 < 128; c0 += 4) {
            int c = c0 + (tid >> 6);
            zl[c][tid & 63] = z[((size_t)(bb * C_ + h * 128 + c)) * HW_ + hw0 + (tid & 63)];
        }
        __syncthreads();
        // zT: transpose out
        for (int it = 0; it < 8; ++it) {
            int rp = it * 8 + wid * 2 + (lane >> 5);
            int c4 = (lane & 31) * 4;
            float4 v = { zl[c4][rp], zl[c4 + 1][rp], zl[c4 + 2][rp], zl[c4 + 3][rp] };
            *(float4*)(zT + (size_t)(n0 + rp) * C_ + h * 128 + c4) = v;
        }
        // Ap: kc = h*2 + q, chunk-local c = q*64 + u*8; zn2 partial alongside
        #pragma unroll
        for (int q = 0; q < 2; ++q) {
            const int kc = h * 2 + q;
            #pragma unroll
            for (int rh = 0; rh < 2; ++rh) {
                int rloc = (tid >> 3) + rh * 32;
                int n = n0 + rloc;
                int r = n & 127;
                u16 tmp[8];
                #pragma unroll
                for (int j = 0; j < 8; ++j) {
                    float f = zl[q * 64 + u * 8 + j][rloc];
                    zacc[rh] += (double)f * (double)f;
                    tmp[j] = f2h(f);
                }
                char* dst = (char*)Ap + ((size_t)((n >> 7) * 4 + kc)) * 16384
                          + r * 128 + ((u * 16) ^ ((r & 7) << 4));
                *(uint4*)dst = *(uint4*)tmp;
            }
        }
    }
    // reduce zn2 across the 8 u-lanes of each row
    #pragma unroll
    for (int rh = 0; rh < 2; ++rh) {
        double a = zacc[rh];
        a += __shfl_xor(a, 1);
        a += __shfl_xor(a, 2);
        a += __shfl_xor(a, 4);
        if (u == 0) zn2g[n0 + (tid >> 3) + rh * 32] = (float)a;
    }
}

// =============== prep_cb: B_prep f16 (e scaled 2^13) + e2 (fused) ============
// grid 128 blocks, 64 codes each.
__global__ __launch_bounds__(256) void vq_prep_cb(const float* __restrict__ cb,
                                                  u16* __restrict__ Bp,
                                                  float* __restrict__ e2g) {
    const int tid = threadIdx.x;
    const int k0 = blockIdx.x * 64;
    const int u = tid & 7;
    for (int h = 0; h < 2; ++h) {
        int rloc = (tid >> 3) + h * 32;
        int k = k0 + rloc;
        int r = k & 127;
        double eacc = 0.0;
        #pragma unroll
        for (int kc = 0; kc < 4; ++kc) {
            const float* src = cb + (size_t)k * C_ + kc * 64 + u * 8;
            float4 v0 = *(const float4*)(src);
            float4 v1 = *(const float4*)(src + 4);
            float vals[8] = { v0.x, v0.y, v0.z, v0.w, v1.x, v1.y, v1.z, v1.w };
            u16 tmp[8];
            #pragma unroll
            for (int j = 0; j < 8; ++j) {
                eacc += (double)vals[j] * (double)vals[j];
                tmp[j] = f2h(vals[j] * 8192.0f);   // exact pow2 scale, then RNE
            }
            char* dst = (char*)Bp + ((size_t)((k >> 7) * 4 + kc)) * 16384
                      + r * 128 + ((u * 16) ^ ((r & 7) << 4));
            *(uint4*)dst = *(uint4*)tmp;
        }
        eacc += __shfl_xor(eacc, 1);
        eacc += __shfl_xor(eacc, 2);
        eacc += __shfl_xor(eacc, 4);
        if (u == 0) e2g[k] = (float)eacc;
    }
}

// =============== main f16 MFMA scorer: top-2 per (row, 64-codes) =============
// 128 codes x 128 rows, K=256 (4 chunks), raw-barrier counted-vmcnt pipeline.
// Chunk->buffer map: chunk kc lives in buf (kc & 1).
__global__ __launch_bounds__(256) void vq_gemm_top2(const u16* __restrict__ Ap,
                                                    const u16* __restrict__ Bp,
                                                    u32* __restrict__ cand) {
    __shared__ char lds[65536];          // 2 bufs x {codes 16K, z 16K}
    const int tid = threadIdx.x;
    const int lane = tid & 63, wid = tid >> 6;
    const int wm = wid >> 1, wn = wid & 1;
    const int l15 = lane & 15, l4 = lane >> 4;

    // L2-aware order: XCD owns 8 n_tiles; 8 consecutive blocks share one m-tile.
    const int raw = blockIdx.x;
    const int m_tile = raw >> 6;                         // 0..255
    const int n_tile = (raw & 7) * 8 + ((raw >> 3) & 7); // 0..63

    f32x4 acc[4][4];
    #pragma unroll
    for (int i = 0; i < 4; ++i)
        #pragma unroll
        for (int j = 0; j < 4; ++j) acc[i][j] = (f32x4){0.f, 0.f, 0.f, 0.f};

    int rc[4], rz[4], xc[4], xz[4];
    #pragma unroll
    for (int f = 0; f < 4; ++f) {
        rc[f] = wm * 64 + f * 16 + l15;
        rz[f] = wn * 64 + f * 16 + l15;
        xc[f] = (rc[f] & 7) << 4;
        xz[f] = (rz[f] & 7) << 4;
    }
    const int ob = l4 * 16;

    const char* codes_src = (const char*)Bp + (size_t)(n_tile * 4) * 16384;
    const char* z_src     = (const char*)Ap + (size_t)(m_tile * 4) * 16384;

    #define STAGE(buf, kc)                                                        \
        do {                                                                      \
            const char* cs_ = codes_src + (size_t)(kc) * 16384;                   \
            const char* zs_ = z_src + (size_t)(kc) * 16384;                       \
            char* lb_ = lds + (buf) * 32768;                                      \
            _Pragma("unroll")                                                     \
            for (int i_ = 0; i_ < 4; ++i_)                                        \
                gload16(cs_ + i_ * 4096 + tid * 16, lb_ + i_ * 4096 + tid * 16);  \
            _Pragma("unroll")                                                     \
            for (int i_ = 0; i_ < 4; ++i_)                                        \
                gload16(zs_ + i_ * 4096 + tid * 16,                               \
                        lb_ + 16384 + i_ * 4096 + tid * 16);                      \
        } while (0)

    #define COMPUTE(buf)                                                          \
        do {                                                                      \
            const char* base_ = lds + (buf) * 32768;                              \
            _Pragma("unroll")                                                     \
            for (int ks = 0; ks < 2; ++ks) {                                      \
                f16x8 la[4], lb[4];                                               \
                _Pragma("unroll")                                                 \
                for (int f = 0; f < 4; ++f) {                                     \
                    la[f] = *(const f16x8*)(base_ + rc[f] * 128                   \
                                            + ((ks * 64 + ob) ^ xc[f]));          \
                    lb[f] = *(const f16x8*)(base_ + 16384 + rz[f] * 128           \
                                            + ((ks * 64 + ob) ^ xz[f]));          \
                }                                                                 \
                _Pragma("unroll")                                                 \
                for (int fm = 0; fm < 4; ++fm)                                    \
                    _Pragma("unroll")                                             \
                    for (int fn = 0; fn < 4; ++fn)                                \
                        acc[fm][fn] = __builtin_amdgcn_mfma_f32_16x16x32_f16(     \
                            la[fm], lb[fn], acc[fm][fn], 0, 0, 0);                \
            }                                                                     \
        } while (0)

    #define FENCE() __builtin_amdgcn_sched_barrier(0)
    #define WAITB(n)                                                              \
        do {                                                                      \
            asm volatile("s_waitcnt vmcnt(" #n ")" ::: "memory");                 \
            FENCE();                                                              \
            __builtin_amdgcn_s_barrier();                                         \
            FENCE();                                                              \
        } while (0)
    #define ENDBAR()                                                              \
        do {                                                                      \
            __builtin_amdgcn_s_barrier();                                         \
            FENCE();                                                              \
        } while (0)

    STAGE(0, 0);
    STAGE(1, 1);
    WAITB(8);        // chunk 0 landed (chunk 1's 8 loads stay in flight)
    COMPUTE(0);      // chunk 0 in buf 0
    ENDBAR();        // all waves done reading buf0
    STAGE(0, 2);
    WAITB(8);        // chunk 1 landed
    COMPUTE(1);      // chunk 1 in buf 1
    ENDBAR();
    STAGE(1, 3);
    WAITB(8);        // chunk 2 landed
    COMPUTE(0);      // chunk 2 in buf 0   (round-4 bug: was COMPUTE(2) -> OOB LDS)
    WAITB(0);        // chunk 3 landed (final drain)
    COMPUTE(1);      // chunk 3 in buf 1   (round-4 bug: was COMPUTE(3) -> OOB LDS)

    #undef STAGE
    #undef COMPUTE
    #undef WAITB
    #undef ENDBAR
    #undef FENCE

    // epilogue: w = 0.5 - s_scaled*2^-12 (positive -> u32 order == float order);
    // clear low 6 mantissa bits, pack 6-bit in-tile idx, track top-2 via min/max.
    const int ktile = n_tile * 2 + wm;
    #pragma unroll
    for (int fn = 0; fn < 4; ++fn) {
        u32 m1 = 0xFFFFFFFFu, m2 = 0xFFFFFFFFu;
        #pragma unroll
        for (int fm = 0; fm < 4; ++fm) {
            #pragma unroll
            for (int rv = 0; rv < 4; ++rv) {
                float w = fmaf(acc[fm][fn][rv], -0x1p-12f, 0.5f);
                u32 p = (__float_as_uint(w) & ~63u) | (u32)(fm * 16 + l4 * 4 + rv);
                u32 t = m1 > p ? m1 : p;
                m1 = m1 < p ? m1 : p;
                m2 = m2 < t ? m2 : t;
            }
        }
        #pragma unroll
        for (int off = 16; off <= 32; off <<= 1) {
            u32 b1 = __shfl_xor(m1, off);
            u32 b2 = __shfl_xor(m2, off);
            u32 t = m1 > b1 ? m1 : b1;
            m1 = m1 < b1 ? m1 : b1;
            u32 s2 = m2 < b2 ? m2 : b2;
            m2 = s2 < t ? s2 : t;
        }
        if (l4 == 0) {
            int rowg = m_tile * 128 + wn * 64 + fn * 16 + l15;
            *(uint2*)(cand + (size_t)rowg * 256 + ktile * 2) = make_uint2(m1, m2);
        }
    }
}

// =============== pick: min + threshold + exact fp64 rescue + idx out =========
// wave per row; candidates via ballot; exact d replicates round-1 arithmetic.
__global__ __launch_bounds__(256) void vq_pick(const u32* __restrict__ cand,
                                               const float* __restrict__ zT,
                                               const float* __restrict__ cb,
                                               const float* __restrict__ e2g,
                                               const float* __restrict__ zn2g,
                                               int* __restrict__ idxg,
                                               float* __restrict__ out) {
    const int lane = threadIdx.x & 63, wid = threadIdx.x >> 6;
    const int row = blockIdx.x * 4 + wid;
    const uint4 e = ((const uint4*)(cand + (size_t)row * 256))[lane];
    u32 m = e.x < e.y ? e.x : e.y;
    u32 mzw = e.z < e.w ? e.z : e.w;
    m = m < mzw ? m : mzw;
    #pragma unroll
    for (int off = 32; off >= 1; off >>= 1) {
        u32 o = __shfl_xor(m, off);
        m = o < m ? o : m;
    }
    const float thr = __uint_as_float(m & ~63u) + THRESH_T;
    const float4 zv = *(const float4*)(zT + (size_t)row * C_ + lane * 4);
    const float zn2a = zn2g[row];
    float bd = INFINITY;
    int bk = 0x7fffffff;
    const u32 ev[4] = { e.x, e.y, e.z, e.w };
    #pragma unroll
    for (int j = 0; j < 4; ++j) {
        u64 msk = __ballot(__uint_as_float(ev[j] & ~63u) <= thr);
        while (msk) {
            const int l = __ffsll((unsigned long long)msk) - 1;
            msk &= msk - 1;
            const u32 val = __shfl(ev[j], l);
            const int k = ((l * 4 + j) >> 1) * 64 + (int)(val & 63u);
            const float4 cv = *(const float4*)(cb + (size_t)k * C_ + lane * 4);
            double s = (double)zv.x * cv.x + (double)zv.y * cv.y
                     + (double)zv.z * cv.z + (double)zv.w * cv.w;
            #pragma unroll
            for (int off = 32; off >= 1; off >>= 1) s += __shfl_xor(s, off);
            const float sf = (float)s;
            const float d = (zn2a + e2g[k]) - 2.0f * sf;
            if (d < bd || (d == bd && k < bk)) { bd = d; bk = k; }
        }
    }
    if (lane == 0) {
        idxg[row] = bk;
        out[8388609 + row] = (float)bk;
    }
}

// =============== z_q (STE mimic, float4) + per-block loss partials ===========
__global__ __launch_bounds__(256) void vq_zq_loss_kernel(const float* __restrict__ z,
                                                         const float* __restrict__ cb,
                                                         const int* __restrict__ idxg,
                                                         float* __restrict__ out,
                                                         double* __restrict__ partial) {
    double acc = 0.0;
    for (size_t i4 = (size_t)blockIdx.x * 256 + threadIdx.x; i4 < 2097152ULL;
         i4 += 2048ULL * 256ULL) {
        const size_t i = i4 * 4;
        const int hw = (int)(i & 4095);
        const int bc = (int)(i >> 12);
        const int c = bc & 255;
        const int b = bc >> 8;
        const int n = (b << 12) + hw;
        const float4 zv = *(const float4*)(z + i);
        const int k0 = idxg[n], k1 = idxg[n + 1], k2 = idxg[n + 2], k3 = idxg[n + 3];
        const float t0 = cb[(size_t)k0 * C_ + c] - zv.x;
        const float t1 = cb[(size_t)k1 * C_ + c] - zv.y;
        const float t2 = cb[(size_t)k2 * C_ + c] - zv.z;
        const float t3 = cb[(size_t)k3 * C_ + c] - zv.w;
        float4 o = { zv.x + t0, zv.y + t1, zv.z + t2, zv.w + t3 };
        *(float4*)(out + i) = o;
        acc += (double)t0 * t0 + (double)t1 * t1 + (double)t2 * t2 + (double)t3 * t3;
    }
    #pragma unroll
    for (int off = 32; off >= 1; off >>= 1) acc += __shfl_xor(acc, off);
    __shared__ double ls[4];
    const int lane = threadIdx.x & 63, wid = threadIdx.x >> 6;
    if (lane == 0) ls[wid] = acc;
    __syncthreads();
    if (threadIdx.x == 0) partial[blockIdx.x] = ls[0] + ls[1] + ls[2] + ls[3];
}

// =============== loss finalize (1 block) =====================================
__global__ __launch_bounds__(256) void vq_loss_final(const double* __restrict__ partial,
                                                     float* __restrict__ out) {
    double acc = 0.0;
    for (int j = threadIdx.x; j < 2048; j += 256) acc += partial[j];
    #pragma unroll
    for (int off = 32; off >= 1; off >>= 1) acc += __shfl_xor(acc, off);
    __shared__ double ls[4];
    const int lane = threadIdx.x & 63, wid = threadIdx.x >> 6;
    if (lane == 0) ls[wid] = acc;
    __syncthreads();
    if (threadIdx.x == 0)
        out[8388608] = (float)(1.25 * (ls[0] + ls[1] + ls[2] + ls[3]) / 8388608.0);
}

// =============== fallback fp64 path (round-1, used if ws too small) ==========
__global__ __launch_bounds__(256) void vq_e2_old(const float* __restrict__ cb,
                                                 float* __restrict__ e2g) {
    int lane = threadIdx.x & 63;
    int w = threadIdx.x >> 6;
    int k = blockIdx.x * 4 + w;
    const float4 v = *reinterpret_cast<const float4*>(cb + (size_t)k * C_ + lane * 4);
    double acc = (double)v.x * v.x + (double)v.y * v.y
               + (double)v.z * v.z + (double)v.w * v.w;
    #pragma unroll
    for (int off = 32; off >= 1; off >>= 1) acc += __shfl_xor(acc, off);
    if (lane == 0) e2g[k] = (float)acc;
}

__global__ __launch_bounds__(256) void vq_zn2_old(const float* __restrict__ z,
                                                  float* __restrict__ zn2g) {
    int n = blockIdx.x * 256 + threadIdx.x;
    int b = n >> 12;
    int hw = n & 4095;
    const float* p = z + (size_t)b * C_ * HW_ + hw;
    double acc = 0.0;
    #pragma unroll 8
    for (int c = 0; c < C_; ++c) {
        float v = p[(size_t)c * HW_];
        acc += (double)v * (double)v;
    }
    zn2g[n] = (float)acc;
}

__global__ __launch_bounds__(256) void vq_argmin_old(const float* __restrict__ z,
                                                     const float* __restrict__ cb,
                                                     const float* __restrict__ e2g,
                                                     const float* __restrict__ zn2g,
                                                     int* __restrict__ idxg) {
    __shared__ float zt[C_][32];
    __shared__ float et[64][64];
    const int tid = threadIdx.x;
    const int n0 = blockIdx.x * 32;
    const int b = n0 >> 12;
    const int hw0 = n0 & 4095;
    {
        const int nn = tid & 31;
        const int c8 = tid >> 5;
        #pragma unroll
        for (int j = 0; j < 32; ++j) {
            const int c = j * 8 + c8;
            zt[c][nn] = z[(size_t)(b * C_ + c) * HW_ + hw0 + nn];
        }
    }
    const int cg = tid & 15;
    const int rg = tid >> 4;
    const int r0 = rg * 2;
    __syncthreads();
    const float zn2a = zn2g[n0 + r0];
    const float zn2b = zn2g[n0 + r0 + 1];
    float dmin0 = INFINITY, dmin1 = INFINITY;
    int imin0 = 0, imin1 = 0;
    const int kk = tid >> 2;
    const int c4 = (tid & 3) * 16;
    for (int kt = 0; kt < K_; kt += 64) {
        double s00 = 0, s01 = 0, s02 = 0, s03 = 0;
        double s10 = 0, s11 = 0, s12 = 0, s13 = 0;
        for (int cc = 0; cc < C_; cc += 64) {
            __syncthreads();
            {
                const float* src = cb + (size_t)(kt + kk) * C_ + cc + c4;
                #pragma unroll
                for (int j = 0; j < 16; j += 4) {
                    const float4 v = *reinterpret_cast<const float4*>(src + j);
                    et[c4 + j + 0][kk] = v.x;
                    et[c4 + j + 1][kk] = v.y;
                    et[c4 + j + 2][kk] = v.z;
                    et[c4 + j + 3][kk] = v.w;
                }
            }
            __syncthreads();
            #pragma unroll 4
            for (int c2 = 0; c2 < 64; ++c2) {
                const float2 zv = *reinterpret_cast<const float2*>(&zt[cc + c2][r0]);
                const float4 ev = *reinterpret_cast<const float4*>(&et[c2][cg * 4]);
                const double z0 = (double)zv.x, z1 = (double)zv.y;
                s00 += z0 * ev.x; s01 += z0 * ev.y; s02 += z0 * ev.z; s03 += z0 * ev.w;
                s10 += z1 * ev.x; s11 += z1 * ev.y; s12 += z1 * ev.z; s13 += z1 * ev.w;
            }
        }
        const int kbase = kt + cg * 4;
        const float sf0[4] = {(float)s00, (float)s01, (float)s02, (float)s03};
        const float sf1[4] = {(float)s10, (float)s11, (float)s12, (float)s13};
        #pragma unroll
        for (int j = 0; j < 4; ++j) {
            const int k = kbase + j;
            const float e2k = e2g[k];
            const float d0 = (zn2a + e2k) - 2.0f * sf0[j];
            const float d1 = (zn2b + e2k) - 2.0f * sf1[j];
            if (d0 < dmin0) { dmin0 = d0; imin0 = k; }
            if (d1 < dmin1) { dmin1 = d1; imin1 = k; }
        }
    }
    #pragma unroll
    for (int off = 8; off >= 1; off >>= 1) {
        const float od0 = __shfl_xor(dmin0, off);
        const int   oi0 = __shfl_xor(imin0, off);
        const float od1 = __shfl_xor(dmin1, off);
        const int   oi1 = __shfl_xor(imin1, off);
        if (od0 < dmin0 || (od0 == dmin0 && oi0 < imin0)) { dmin0 = od0; imin0 = oi0; }
        if (od1 < dmin1 || (od1 == dmin1 && oi1 < imin1)) { dmin1 = od1; imin1 = oi1; }
    }
    if (cg == 0) {
        idxg[n0 + r0]     = imin0;
        idxg[n0 + r0 + 1] = imin1;
    }
}

__global__ __launch_bounds__(256) void vq_final_old(const int* __restrict__ idxg,
                                                    float* __restrict__ out) {
    const int i = blockIdx.x * 256 + threadIdx.x;
    out[8388609 + i] = (float)idxg[i];
}

extern "C" void kernel_launch(void* const* d_in, const int* in_sizes, int n_in,
                              void* d_out, int out_size, void* d_ws, size_t ws_size,
                              hipStream_t stream) {
    const float* z  = (const float*)d_in[0];
    const float* cb = (const float*)d_in[1];
    float* out = (float*)d_out;
    char* ws = (char*)d_ws;

    double* lossp = (double*)(ws + O_LOSSP);
    float*  e2g  = (float*)(ws + O_E2);
    float*  zn2g = (float*)(ws + O_ZN2);
    int*    idxg = (int*)(ws + O_IDX);

    if (ws_size >= WS_NEED) {
        float* zT   = (float*)(ws + O_ZT);
        u16*   Ap   = (u16*)(ws + O_AP);
        u16*   Bp   = (u16*)(ws + O_BP);
        u32*   cand = (u32*)(ws + O_CAND);

        hipLaunchKernelGGL(vq_prep_cb, dim3(128), dim3(256), 0, stream, cb, Bp, e2g);
        hipLaunchKernelGGL(vq_prep_z, dim3(512), dim3(256), 0, stream, z, zT, Ap, zn2g);
        hipLaunchKernelGGL(vq_gemm_top2, dim3(16384), dim3(256), 0, stream, Ap, Bp, cand);
        hipLaunchKernelGGL(vq_pick, dim3(N_ / 4), dim3(256), 0, stream,
                           cand, zT, cb, e2g, zn2g, idxg, out);
    } else {
        hipLaunchKernelGGL(vq_e2_old, dim3(K_ / 4), dim3(256), 0, stream, cb, e2g);
        hipLaunchKernelGGL(vq_zn2_old, dim3(N_ / 256), dim3(256), 0, stream, z, zn2g);
        hipLaunchKernelGGL(vq_argmin_old, dim3(N_ / 32), dim3(256), 0, stream,
                           z, cb, e2g, zn2g, idxg);
        hipLaunchKernelGGL(vq_final_old, dim3(N_ / 256), dim3(256), 0, stream, idxg, out);
    }

    hipLaunchKernelGGL(vq_zq_loss_kernel, dim3(2048), dim3(256), 0, stream,
                       z, cb, idxg, out, lossp);
    hipLaunchKernelGGL(vq_loss_final, dim3(1), dim3(256), 0, stream, lossp, out);
}

// Round 7
// 227.157 us; speedup vs baseline: 21.2613x; 1.0784x over previous
//
#include <hip/hip_runtime.h>
#include <hip/hip_bf16.h>
#include <math.h>

typedef unsigned short u16;
typedef unsigned int u32;
typedef unsigned long long u64;
typedef __attribute__((ext_vector_type(8))) _Float16 f16x8;
typedef __attribute__((ext_vector_type(4))) float f32x4;

#define B_   8
#define C_   256
#define HW_  4096
#define N_   32768
#define K_   8192

// ---- ws layout (bytes) ----
#define O_LOSSP 0ULL            // 2048 doubles
#define O_E2    16384ULL        // 8192 f32
#define O_ZN2   49152ULL        // 32768 f32
#define O_IDX   180224ULL       // 32768 i32
#define O_ZT    311296ULL       // 32768*256 f32
#define O_AP    33865728ULL     // 256 tiles * 8 chunks * 8KB (f16)
#define O_BP    50642944ULL     // 64 tiles * 8 chunks * 8KB (f16)
#define O_CAND  54837248ULL     // 32768*128*2 u32
#define WS_NEED 88391680ULL

#define THRESH_T 9e-5f

__device__ __forceinline__ u16 f2h(float f) {
    _Float16 h = (_Float16)f;                 // v_cvt_f16_f32, RNE, deterministic
    return __builtin_bit_cast(u16, h);
}

__device__ __forceinline__ void gload16(const void* g, void* l) {
    __builtin_amdgcn_global_load_lds((const __attribute__((address_space(1))) void*)g,
                                     (__attribute__((address_space(3))) void*)l, 16, 0, 0);
}

// Tile layout (both Ap and Bp): [tile(128 rows)][chunk kc8 of 8][128 rows x 64B]
// row r holds K-groups u4 (8 f16 each) at byte (u4*16) ^ ((r&3)<<4).

// =============== prep_z: zT fp32 + A_prep f16 + zn2 (fused) ==================
// grid 512 = 8 b * 64 hw-chunks, 256 thr.
__global__ __launch_bounds__(256) void vq_prep_z(const float* __restrict__ z,
                                                 float* __restrict__ zT,
                                                 u16* __restrict__ Ap,
                                                 float* __restrict__ zn2g) {
    __shared__ float zl[128][65];
    const int tid = threadIdx.x;
    const int bb = blockIdx.x >> 6;
    const int hwc = blockIdx.x & 63;
    const int hw0 = hwc * 64;
    const int n0 = bb * HW_ + hw0;
    const int lane = tid & 63, wid = tid >> 6;
    const int r = tid >> 2;         // 0..63 row within block
    const int u4 = tid & 3;         // K-group slot
    const int n = n0 + r;
    const int r7 = n & 127;         // row within 128-row tile
    double zacc = 0.0;

    for (int h = 0; h < 2; ++h) {
        __syncthreads();
        for (int c0 = 0; c0 < 128; c0 += 4) {
            int c = c0 + (tid >> 6);
            zl[c][tid & 63] = z[((size_t)(bb * C_ + h * 128 + c)) * HW_ + hw0 + (tid & 63)];
        }
        __syncthreads();
        // zT: transpose out
        for (int it = 0; it < 8; ++it) {
            int rp = it * 8 + wid * 2 + (lane >> 5);
            int c4 = (lane & 31) * 4;
            float4 v = { zl[c4][rp], zl[c4 + 1][rp], zl[c4 + 2][rp], zl[c4 + 3][rp] };
            *(float4*)(zT + (size_t)(n0 + rp) * C_ + h * 128 + c4) = v;
        }
        // Ap chunks kc8 = h*4 + q ; local c = q*32 + u4*8 + j
        #pragma unroll
        for (int q = 0; q < 4; ++q) {
            u16 tmp[8];
            #pragma unroll
            for (int j = 0; j < 8; ++j) {
                float f = zl[q * 32 + u4 * 8 + j][r];
                zacc += (double)f * (double)f;
                tmp[j] = f2h(f);
            }
            char* dst = (char*)Ap + ((size_t)((n >> 7) * 8 + h * 4 + q)) * 8192
                      + r7 * 64 + ((u4 * 16) ^ ((r7 & 3) << 4));
            *(uint4*)dst = *(uint4*)tmp;
        }
    }
    // reduce zn2 across the 4 u4-lanes of each row
    zacc += __shfl_xor(zacc, 1);
    zacc += __shfl_xor(zacc, 2);
    if (u4 == 0) zn2g[n] = (float)zacc;
}

// =============== prep_cb: B_prep f16 (e scaled 2^13) + e2 (fused) ============
// grid 128 blocks, 64 codes each.
__global__ __launch_bounds__(256) void vq_prep_cb(const float* __restrict__ cb,
                                                  u16* __restrict__ Bp,
                                                  float* __restrict__ e2g) {
    const int tid = threadIdx.x;
    const int k0 = blockIdx.x * 64;
    const int r = tid >> 2;
    const int u4 = tid & 3;
    const int k = k0 + r;
    const int r7 = k & 127;
    double eacc = 0.0;
    #pragma unroll
    for (int kc8 = 0; kc8 < 8; ++kc8) {
        const float* src = cb + (size_t)k * C_ + kc8 * 32 + u4 * 8;
        float4 v0 = *(const float4*)(src);
        float4 v1 = *(const float4*)(src + 4);
        float vals[8] = { v0.x, v0.y, v0.z, v0.w, v1.x, v1.y, v1.z, v1.w };
        u16 tmp[8];
        #pragma unroll
        for (int j = 0; j < 8; ++j) {
            eacc += (double)vals[j] * (double)vals[j];
            tmp[j] = f2h(vals[j] * 8192.0f);   // exact pow2 scale, then RNE
        }
        char* dst = (char*)Bp + ((size_t)((k >> 7) * 8 + kc8)) * 8192
                  + r7 * 64 + ((u4 * 16) ^ ((r7 & 3) << 4));
        *(uint4*)dst = *(uint4*)tmp;
    }
    eacc += __shfl_xor(eacc, 1);
    eacc += __shfl_xor(eacc, 2);
    if (u4 == 0) e2g[k] = (float)eacc;
}

// =============== main f16 MFMA scorer: top-2 per (row, 64-codes) =============
// 128 codes x 128 rows, BK=32 (8 chunks), 32KB dbuf LDS -> 5 blocks/CU.
// Correct-by-construction pipeline: ONE __syncthreads per chunk (drains
// vmcnt0+lgkmcnt0 in every wave => staged chunk landed AND previous chunk's
// ds_reads done before the other buffer is overwritten). Prefetch issued
// after the barrier, before COMPUTE, so load latency hides under MFMA;
// cross-block TLP (5 blocks/CU) covers the per-phase drain.
__global__ __launch_bounds__(256) void vq_gemm_top2(const u16* __restrict__ Ap,
                                                    const u16* __restrict__ Bp,
                                                    u32* __restrict__ cand) {
    __shared__ char lds[32768];          // 2 bufs x {codes 8K, z 8K}
    const int tid = threadIdx.x;
    const int lane = tid & 63, wid = tid >> 6;
    const int wm = wid >> 1, wn = wid & 1;
    const int l15 = lane & 15, l4 = lane >> 4;

    // L2-aware order: XCD owns 8 n_tiles; 8 consecutive blocks share one m-tile.
    const int raw = blockIdx.x;
    const int m_tile = raw >> 6;                         // 0..255
    const int n_tile = (raw & 7) * 8 + ((raw >> 3) & 7); // 0..63

    f32x4 acc[4][4];
    #pragma unroll
    for (int i = 0; i < 4; ++i)
        #pragma unroll
        for (int j = 0; j < 4; ++j) acc[i][j] = (f32x4){0.f, 0.f, 0.f, 0.f};

    int rc[4], rz[4], xc[4], xz[4];
    #pragma unroll
    for (int f = 0; f < 4; ++f) {
        rc[f] = wm * 64 + f * 16 + l15;
        rz[f] = wn * 64 + f * 16 + l15;
        xc[f] = (rc[f] & 3) << 4;
        xz[f] = (rz[f] & 3) << 4;
    }
    const int ob = l4 * 16;

    const char* codes_src = (const char*)Bp + (size_t)n_tile * 65536;
    const char* z_src     = (const char*)Ap + (size_t)m_tile * 65536;

    #define STAGE(buf, kc)                                                        \
        do {                                                                      \
            const char* cs_ = codes_src + (size_t)(kc) * 8192;                    \
            const char* zs_ = z_src + (size_t)(kc) * 8192;                        \
            char* lb_ = lds + (buf) * 16384;                                      \
            gload16(cs_ + tid * 16, lb_ + tid * 16);                              \
            gload16(cs_ + 4096 + tid * 16, lb_ + 4096 + tid * 16);                \
            gload16(zs_ + tid * 16, lb_ + 8192 + tid * 16);                       \
            gload16(zs_ + 4096 + tid * 16, lb_ + 12288 + tid * 16);               \
        } while (0)

    #define COMPUTE(buf)                                                          \
        do {                                                                      \
            const char* base_ = lds + (buf) * 16384;                              \
            f16x8 la[4], lb[4];                                                   \
            _Pragma("unroll")                                                     \
            for (int f = 0; f < 4; ++f) {                                         \
                la[f] = *(const f16x8*)(base_ + rc[f] * 64 + (ob ^ xc[f]));       \
                lb[f] = *(const f16x8*)(base_ + 8192 + rz[f] * 64 + (ob ^ xz[f]));\
            }                                                                     \
            _Pragma("unroll")                                                     \
            for (int fm = 0; fm < 4; ++fm)                                        \
                _Pragma("unroll")                                                 \
                for (int fn = 0; fn < 4; ++fn)                                    \
                    acc[fm][fn] = __builtin_amdgcn_mfma_f32_16x16x32_f16(         \
                        la[fm], lb[fn], acc[fm][fn], 0, 0, 0);                    \
        } while (0)

    STAGE(0, 0);
    #pragma unroll
    for (int kc = 0; kc < 8; ++kc) {
        __syncthreads();                       // chunk kc landed; prev reads done
        if (kc < 7) STAGE((kc + 1) & 1, kc + 1);
        COMPUTE(kc & 1);
    }

    #undef STAGE
    #undef COMPUTE

    // epilogue: w = 0.5 - s_scaled*2^-12 (positive -> u32 order == float order);
    // clear low 6 mantissa bits, pack 6-bit in-tile idx, track top-2 via min/max.
    const int ktile = n_tile * 2 + wm;
    #pragma unroll
    for (int fn = 0; fn < 4; ++fn) {
        u32 m1 = 0xFFFFFFFFu, m2 = 0xFFFFFFFFu;
        #pragma unroll
        for (int fm = 0; fm < 4; ++fm) {
            #pragma unroll
            for (int rv = 0; rv < 4; ++rv) {
                float w = fmaf(acc[fm][fn][rv], -0x1p-12f, 0.5f);
                u32 p = (__float_as_uint(w) & ~63u) | (u32)(fm * 16 + l4 * 4 + rv);
                u32 t = m1 > p ? m1 : p;
                m1 = m1 < p ? m1 : p;
                m2 = m2 < t ? m2 : t;
            }
        }
        #pragma unroll
        for (int off = 16; off <= 32; off <<= 1) {
            u32 b1 = __shfl_xor(m1, off);
            u32 b2 = __shfl_xor(m2, off);
            u32 t = m1 > b1 ? m1 : b1;
            m1 = m1 < b1 ? m1 : b1;
            u32 s2 = m2 < b2 ? m2 : b2;
            m2 = s2 < t ? s2 : t;
        }
        if (l4 == 0) {
            int rowg = m_tile * 128 + wn * 64 + fn * 16 + l15;
            *(uint2*)(cand + (size_t)rowg * 256 + ktile * 2) = make_uint2(m1, m2);
        }
    }
}

// =============== pick: min + threshold + exact fp64 rescue + idx out =========
// wave per row. Fast path: exactly 1 candidate under thr -> it IS the argmin
// (unconditionally equivalent to slow path: slow path would evaluate exactly
// that single candidate).
__global__ __launch_bounds__(256) void vq_pick(const u32* __restrict__ cand,
                                               const float* __restrict__ zT,
                                               const float* __restrict__ cb,
                                               const float* __restrict__ e2g,
                                               const float* __restrict__ zn2g,
                                               int* __restrict__ idxg,
                                               float* __restrict__ out) {
    const int lane = threadIdx.x & 63, wid = threadIdx.x >> 6;
    const int row = blockIdx.x * 4 + wid;
    const uint4 e = ((const uint4*)(cand + (size_t)row * 256))[lane];
    u32 m = e.x < e.y ? e.x : e.y;
    u32 mzw = e.z < e.w ? e.z : e.w;
    m = m < mzw ? m : mzw;
    #pragma unroll
    for (int off = 32; off >= 1; off >>= 1) {
        u32 o = __shfl_xor(m, off);
        m = o < m ? o : m;
    }
    const float thr = __uint_as_float(m & ~63u) + THRESH_T;
    const u32 ev[4] = { e.x, e.y, e.z, e.w };
    u64 msk[4];
    int tot = 0;
    #pragma unroll
    for (int j = 0; j < 4; ++j) {
        msk[j] = __ballot(__uint_as_float(ev[j] & ~63u) <= thr);
        tot += __popcll((unsigned long long)msk[j]);
    }
    int bk;
    if (tot == 1) {
        const int j = msk[0] ? 0 : (msk[1] ? 1 : (msk[2] ? 2 : 3));
        const int l = __ffsll((unsigned long long)msk[j]) - 1;
        const u32 val = __shfl(ev[j], l);
        bk = ((l * 4 + j) >> 1) * 64 + (int)(val & 63u);
    } else {
        const float4 zv = *(const float4*)(zT + (size_t)row * C_ + lane * 4);
        const float zn2a = zn2g[row];
        float bd = INFINITY;
        bk = 0x7fffffff;
        #pragma unroll
        for (int j = 0; j < 4; ++j) {
            u64 mj = msk[j];
            while (mj) {
                const int l = __ffsll((unsigned long long)mj) - 1;
                mj &= mj - 1;
                const u32 val = __shfl(ev[j], l);
                const int k = ((l * 4 + j) >> 1) * 64 + (int)(val & 63u);
                const float4 cv = *(const float4*)(cb + (size_t)k * C_ + lane * 4);
                double s = (double)zv.x * cv.x + (double)zv.y * cv.y
                         + (double)zv.z * cv.z + (double)zv.w * cv.w;
                #pragma unroll
                for (int off = 32; off >= 1; off >>= 1) s += __shfl_xor(s, off);
                const float sf = (float)s;
                const float d = (zn2a + e2g[k]) - 2.0f * sf;
                if (d < bd || (d == bd && k < bk)) { bd = d; bk = k; }
            }
        }
    }
    if (lane == 0) {
        idxg[row] = bk;
        out[8388609 + row] = (float)bk;
    }
}

// =============== z_q (STE mimic, float4) + per-block loss partials ===========
__global__ __launch_bounds__(256) void vq_zq_loss_kernel(const float* __restrict__ z,
                                                         const float* __restrict__ cb,
                                                         const int* __restrict__ idxg,
                                                         float* __restrict__ out,
                                                         double* __restrict__ partial) {
    double acc = 0.0;
    for (size_t i4 = (size_t)blockIdx.x * 256 + threadIdx.x; i4 < 2097152ULL;
         i4 += 2048ULL * 256ULL) {
        const size_t i = i4 * 4;
        const int hw = (int)(i & 4095);
        const int bc = (int)(i >> 12);
        const int c = bc & 255;
        const int b = bc >> 8;
        const int n = (b << 12) + hw;
        const float4 zv = *(const float4*)(z + i);
        const int k0 = idxg[n], k1 = idxg[n + 1], k2 = idxg[n + 2], k3 = idxg[n + 3];
        const float t0 = cb[(size_t)k0 * C_ + c] - zv.x;
        const float t1 = cb[(size_t)k1 * C_ + c] - zv.y;
        const float t2 = cb[(size_t)k2 * C_ + c] - zv.z;
        const float t3 = cb[(size_t)k3 * C_ + c] - zv.w;
        float4 o = { zv.x + t0, zv.y + t1, zv.z + t2, zv.w + t3 };
        *(float4*)(out + i) = o;
        acc += (double)t0 * t0 + (double)t1 * t1 + (double)t2 * t2 + (double)t3 * t3;
    }
    #pragma unroll
    for (int off = 32; off >= 1; off >>= 1) acc += __shfl_xor(acc, off);
    __shared__ double ls[4];
    const int lane = threadIdx.x & 63, wid = threadIdx.x >> 6;
    if (lane == 0) ls[wid] = acc;
    __syncthreads();
    if (threadIdx.x == 0) partial[blockIdx.x] = ls[0] + ls[1] + ls[2] + ls[3];
}

// =============== loss finalize (1 block) =====================================
__global__ __launch_bounds__(256) void vq_loss_final(const double* __restrict__ partial,
                                                     float* __restrict__ out) {
    double acc = 0.0;
    for (int j = threadIdx.x; j < 2048; j += 256) acc += partial[j];
    #pragma unroll
    for (int off = 32; off >= 1; off >>= 1) acc += __shfl_xor(acc, off);
    __shared__ double ls[4];
    const int lane = threadIdx.x & 63, wid = threadIdx.x >> 6;
    if (lane == 0) ls[wid] = acc;
    __syncthreads();
    if (threadIdx.x == 0)
        out[8388608] = (float)(1.25 * (ls[0] + ls[1] + ls[2] + ls[3]) / 8388608.0);
}

// =============== fallback fp64 path (round-1, used if ws too small) ==========
__global__ __launch_bounds__(256) void vq_e2_old(const float* __restrict__ cb,
                                                 float* __restrict__ e2g) {
    int lane = threadIdx.x & 63;
    int w = threadIdx.x >> 6;
    int k = blockIdx.x * 4 + w;
    const float4 v = *reinterpret_cast<const float4*>(cb + (size_t)k * C_ + lane * 4);
    double acc = (double)v.x * v.x + (double)v.y * v.y
               + (double)v.z * v.z + (double)v.w * v.w;
    #pragma unroll
    for (int off = 32; off >= 1; off >>= 1) acc += __shfl_xor(acc, off);
    if (lane == 0) e2g[k] = (float)acc;
}

__global__ __launch_bounds__(256) void vq_zn2_old(const float* __restrict__ z,
                                                  float* __restrict__ zn2g) {
    int n = blockIdx.x * 256 + threadIdx.x;
    int b = n >> 12;
    int hw = n & 4095;
    const float* p = z + (size_t)b * C_ * HW_ + hw;
    double acc = 0.0;
    #pragma unroll 8
    for (int c = 0; c < C_; ++c) {
        float v = p[(size_t)c * HW_];
        acc += (double)v * (double)v;
    }
    zn2g[n] = (float)acc;
}

__global__ __launch_bounds__(256) void vq_argmin_old(const float* __restrict__ z,
                                                     const float* __restrict__ cb,
                                                     const float* __restrict__ e2g,
                                                     const float* __restrict__ zn2g,
                                                     int* __restrict__ idxg) {
    __shared__ float zt[C_][32];
    __shared__ float et[64][64];
    const int tid = threadIdx.x;
    const int n0 = blockIdx.x * 32;
    const int b = n0 >> 12;
    const int hw0 = n0 & 4095;
    {
        const int nn = tid & 31;
        const int c8 = tid >> 5;
        #pragma unroll
        for (int j = 0; j < 32; ++j) {
            const int c = j * 8 + c8;
            zt[c][nn] = z[(size_t)(b * C_ + c) * HW_ + hw0 + nn];
        }
    }
    const int cg = tid & 15;
    const int rg = tid >> 4;
    const int r0 = rg * 2;
    __syncthreads();
    const float zn2a = zn2g[n0 + r0];
    const float zn2b = zn2g[n0 + r0 + 1];
    float dmin0 = INFINITY, dmin1 = INFINITY;
    int imin0 = 0, imin1 = 0;
    const int kk = tid >> 2;
    const int c4 = (tid & 3) * 16;
    for (int kt = 0; kt < K_; kt += 64) {
        double s00 = 0, s01 = 0, s02 = 0, s03 = 0;
        double s10 = 0, s11 = 0, s12 = 0, s13 = 0;
        for (int cc = 0; cc < C_; cc += 64) {
            __syncthreads();
            {
                const float* src = cb + (size_t)(kt + kk) * C_ + cc + c4;
                #pragma unroll
                for (int j = 0; j < 16; j += 4) {
                    const float4 v = *reinterpret_cast<const float4*>(src + j);
                    et[c4 + j + 0][kk] = v.x;
                    et[c4 + j + 1][kk] = v.y;
                    et[c4 + j + 2][kk] = v.z;
                    et[c4 + j + 3][kk] = v.w;
                }
            }
            __syncthreads();
            #pragma unroll 4
            for (int c2 = 0; c2 < 64; ++c2) {
                const float2 zv = *reinterpret_cast<const float2*>(&zt[cc + c2][r0]);
                const float4 ev = *reinterpret_cast<const float4*>(&et[c2][cg * 4]);
                const double z0 = (double)zv.x, z1 = (double)zv.y;
                s00 += z0 * ev.x; s01 += z0 * ev.y; s02 += z0 * ev.z; s03 += z0 * ev.w;
                s10 += z1 * ev.x; s11 += z1 * ev.y; s12 += z1 * ev.z; s13 += z1 * ev.w;
            }
        }
        const int kbase = kt + cg * 4;
        const float sf0[4] = {(float)s00, (float)s01, (float)s02, (float)s03};
        const float sf1[4] = {(float)s10, (float)s11, (float)s12, (float)s13};
        #pragma unroll
        for (int j = 0; j < 4; ++j) {
            const int k = kbase + j;
            const float e2k = e2g[k];
            const float d0 = (zn2a + e2k) - 2.0f * sf0[j];
            const float d1 = (zn2b + e2k) - 2.0f * sf1[j];
            if (d0 < dmin0) { dmin0 = d0; imin0 = k; }
            if (d1 < dmin1) { dmin1 = d1; imin1 = k; }
        }
    }
    #pragma unroll
    for (int off = 8; off >= 1; off >>= 1) {
        const float od0 = __shfl_xor(dmin0, off);
        const int   oi0 = __shfl_xor(imin0, off);
        const float od1 = __shfl_xor(dmin1, off);
        const int   oi1 = __shfl_xor(imin1, off);
        if (od0 < dmin0 || (od0 == dmin0 && oi0 < imin0)) { dmin0 = od0; imin0 = oi0; }
        if (od1 < dmin1 || (od1 == dmin1 && oi1 < imin1)) { dmin1 = od1; imin1 = oi1; }
    }
    if (cg == 0) {
        idxg[n0 + r0]     = imin0;
        idxg[n0 + r0 + 1] = imin1;
    }
}

__global__ __launch_bounds__(256) void vq_final_old(const int* __restrict__ idxg,
                                                    float* __restrict__ out) {
    const int i = blockIdx.x * 256 + threadIdx.x;
    out[8388609 + i] = (float)idxg[i];
}

extern "C" void kernel_launch(void* const* d_in, const int* in_sizes, int n_in,
                              void* d_out, int out_size, void* d_ws, size_t ws_size,
                              hipStream_t stream) {
    const float* z  = (const float*)d_in[0];
    const float* cb = (const float*)d_in[1];
    float* out = (float*)d_out;
    char* ws = (char*)d_ws;

    double* lossp = (double*)(ws + O_LOSSP);
    float*  e2g  = (float*)(ws + O_E2);
    float*  zn2g = (float*)(ws + O_ZN2);
    int*    idxg = (int*)(ws + O_IDX);

    if (ws_size >= WS_NEED) {
        float* zT   = (float*)(ws + O_ZT);
        u16*   Ap   = (u16*)(ws + O_AP);
        u16*   Bp   = (u16*)(ws + O_BP);
        u32*   cand = (u32*)(ws + O_CAND);

        hipLaunchKernelGGL(vq_prep_cb, dim3(128), dim3(256), 0, stream, cb, Bp, e2g);
        hipLaunchKernelGGL(vq_prep_z, dim3(512), dim3(256), 0, stream, z, zT, Ap, zn2g);
        hipLaunchKernelGGL(vq_gemm_top2, dim3(16384), dim3(256), 0, stream, Ap, Bp, cand);
        hipLaunchKernelGGL(vq_pick, dim3(N_ / 4), dim3(256), 0, stream,
                           cand, zT, cb, e2g, zn2g, idxg, out);
    } else {
        hipLaunchKernelGGL(vq_e2_old, dim3(K_ / 4), dim3(256), 0, stream, cb, e2g);
        hipLaunchKernelGGL(vq_zn2_old, dim3(N_ / 256), dim3(256), 0, stream, z, zn2g);
        hipLaunchKernelGGL(vq_argmin_old, dim3(N_ / 32), dim3(256), 0, stream,
                           z, cb, e2g, zn2g, idxg);
        hipLaunchKernelGGL(vq_final_old, dim3(N_ / 256), dim3(256), 0, stream, idxg, out);
    }

    hipLaunchKernelGGL(vq_zq_loss_kernel, dim3(2048), dim3(256), 0, stream,
                       z, cb, idxg, out, lossp);
    hipLaunchKernelGGL(vq_loss_final, dim3(1), dim3(256), 0, stream, lossp, out);
}

// Round 8
// 223.607 us; speedup vs baseline: 21.5988x; 1.0159x over previous
//
#include <hip/hip_runtime.h>
#include <hip/hip_bf16.h>
#include <math.h>

typedef unsigned short u16;
typedef unsigned int u32;
typedef unsigned long long u64;
typedef __attribute__((ext_vector_type(8))) _Float16 f16x8;
typedef __attribute__((ext_vector_type(4))) float f32x4;

#define B_   8
#define C_   256
#define HW_  4096
#define N_   32768
#define K_   8192

// ---- ws layout (bytes) ----
#define O_LOSSP 0ULL            // 2048 doubles
#define O_E2    16384ULL        // 8192 f32
#define O_ZN2   49152ULL        // 32768 f32
#define O_IDX   180224ULL       // 32768 i32
#define O_ZT    311296ULL       // 32768*256 f32
#define O_AP    33865728ULL     // 256 tiles * 8 chunks * 8KB (f16)
#define O_BP    50642944ULL     // 64 tiles * 8 chunks * 8KB (f16)
#define O_CAND  54837248ULL     // 32768*128*2 u32
#define WS_NEED 88391680ULL

#define THRESH_T 9e-5f

// LDS bank swizzle: slot(row) = (row>>1)&3. Store at byte (u4*16)^(g<<4),
// read at (l4*16)^(g<<4) -> retrieves K-group l4. Per 16-row fragment read,
// each (parity, slot) bank class gets exactly 2 rows -> 2-way (free, m136).
// Round-7 g=(r&3) gave 4 rows/class -> 4-way conflict (1.68e7 measured).
#define GSWZ(r) (((r) >> 1) & 3)

__device__ __forceinline__ u16 f2h(float f) {
    _Float16 h = (_Float16)f;                 // v_cvt_f16_f32, RNE, deterministic
    return __builtin_bit_cast(u16, h);
}

__device__ __forceinline__ void gload16(const void* g, void* l) {
    __builtin_amdgcn_global_load_lds((const __attribute__((address_space(1))) void*)g,
                                     (__attribute__((address_space(3))) void*)l, 16, 0, 0);
}

// Tile layout (both Ap and Bp): [tile(128 rows)][chunk kc8 of 8][128 rows x 64B]
// row r holds K-group u4 (8 f16) at byte (u4*16) ^ (GSWZ(r)<<4).

// =============== prep_z: zT fp32 + A_prep f16 + zn2 (fused) ==================
// grid 512 = 8 b * 64 hw-chunks, 256 thr.
__global__ __launch_bounds__(256) void vq_prep_z(const float* __restrict__ z,
                                                 float* __restrict__ zT,
                                                 u16* __restrict__ Ap,
                                                 float* __restrict__ zn2g) {
    __shared__ float zl[128][65];
    const int tid = threadIdx.x;
    const int bb = blockIdx.x >> 6;
    const int hwc = blockIdx.x & 63;
    const int hw0 = hwc * 64;
    const int n0 = bb * HW_ + hw0;
    const int lane = tid & 63, wid = tid >> 6;
    const int r = tid >> 2;         // 0..63 row within block
    const int u4 = tid & 3;         // K-group slot
    const int n = n0 + r;
    const int r7 = n & 127;         // row within 128-row tile
    double zacc = 0.0;

    for (int h = 0; h < 2; ++h) {
        __syncthreads();
        for (int c0 = 0; c0 < 128; c0 += 4) {
            int c = c0 + (tid >> 6);
            zl[c][tid & 63] = z[((size_t)(bb * C_ + h * 128 + c)) * HW_ + hw0 + (tid & 63)];
        }
        __syncthreads();
        // zT: transpose out
        for (int it = 0; it < 8; ++it) {
            int rp = it * 8 + wid * 2 + (lane >> 5);
            int c4 = (lane & 31) * 4;
            float4 v = { zl[c4][rp], zl[c4 + 1][rp], zl[c4 + 2][rp], zl[c4 + 3][rp] };
            *(float4*)(zT + (size_t)(n0 + rp) * C_ + h * 128 + c4) = v;
        }
        // Ap chunks kc8 = h*4 + q ; local c = q*32 + u4*8 + j
        #pragma unroll
        for (int q = 0; q < 4; ++q) {
            u16 tmp[8];
            #pragma unroll
            for (int j = 0; j < 8; ++j) {
                float f = zl[q * 32 + u4 * 8 + j][r];
                zacc += (double)f * (double)f;
                tmp[j] = f2h(f);
            }
            char* dst = (char*)Ap + ((size_t)((n >> 7) * 8 + h * 4 + q)) * 8192
                      + r7 * 64 + ((u4 * 16) ^ (GSWZ(r7) << 4));
            *(uint4*)dst = *(uint4*)tmp;
        }
    }
    // reduce zn2 across the 4 u4-lanes of each row
    zacc += __shfl_xor(zacc, 1);
    zacc += __shfl_xor(zacc, 2);
    if (u4 == 0) zn2g[n] = (float)zacc;
}

// =============== prep_cb: B_prep f16 (e scaled 2^13) + e2 (fused) ============
// grid 128 blocks, 64 codes each.
__global__ __launch_bounds__(256) void vq_prep_cb(const float* __restrict__ cb,
                                                  u16* __restrict__ Bp,
                                                  float* __restrict__ e2g) {
    const int tid = threadIdx.x;
    const int k0 = blockIdx.x * 64;
    const int r = tid >> 2;
    const int u4 = tid & 3;
    const int k = k0 + r;
    const int r7 = k & 127;
    double eacc = 0.0;
    #pragma unroll
    for (int kc8 = 0; kc8 < 8; ++kc8) {
        const float* src = cb + (size_t)k * C_ + kc8 * 32 + u4 * 8;
        float4 v0 = *(const float4*)(src);
        float4 v1 = *(const float4*)(src + 4);
        float vals[8] = { v0.x, v0.y, v0.z, v0.w, v1.x, v1.y, v1.z, v1.w };
        u16 tmp[8];
        #pragma unroll
        for (int j = 0; j < 8; ++j) {
            eacc += (double)vals[j] * (double)vals[j];
            tmp[j] = f2h(vals[j] * 8192.0f);   // exact pow2 scale, then RNE
        }
        char* dst = (char*)Bp + ((size_t)((k >> 7) * 8 + kc8)) * 8192
                  + r7 * 64 + ((u4 * 16) ^ (GSWZ(r7) << 4));
        *(uint4*)dst = *(uint4*)tmp;
    }
    eacc += __shfl_xor(eacc, 1);
    eacc += __shfl_xor(eacc, 2);
    if (u4 == 0) e2g[k] = (float)eacc;
}

// =============== main f16 MFMA scorer: top-2 per (row, 64-codes) =============
// 128 codes x 128 rows, BK=32 (8 chunks), 32KB dbuf LDS.
// ONE __syncthreads per chunk (drains vmcnt0+lgkmcnt0 in every wave =>
// staged chunk landed AND previous chunk's ds_reads done before overwrite).
__global__ __launch_bounds__(256) void vq_gemm_top2(const u16* __restrict__ Ap,
                                                    const u16* __restrict__ Bp,
                                                    u32* __restrict__ cand) {
    __shared__ char lds[32768];          // 2 bufs x {codes 8K, z 8K}
    const int tid = threadIdx.x;
    const int lane = tid & 63, wid = tid >> 6;
    const int wm = wid >> 1, wn = wid & 1;
    const int l15 = lane & 15, l4 = lane >> 4;

    // L2-aware order: XCD owns 8 n_tiles; 8 consecutive blocks share one m-tile.
    const int raw = blockIdx.x;
    const int m_tile = raw >> 6;                         // 0..255
    const int n_tile = (raw & 7) * 8 + ((raw >> 3) & 7); // 0..63

    f32x4 acc[4][4];
    #pragma unroll
    for (int i = 0; i < 4; ++i)
        #pragma unroll
        for (int j = 0; j < 4; ++j) acc[i][j] = (f32x4){0.f, 0.f, 0.f, 0.f};

    int rc[4], rz[4], xc[4], xz[4];
    #pragma unroll
    for (int f = 0; f < 4; ++f) {
        rc[f] = wm * 64 + f * 16 + l15;
        rz[f] = wn * 64 + f * 16 + l15;
        xc[f] = GSWZ(rc[f]) << 4;
        xz[f] = GSWZ(rz[f]) << 4;
    }
    const int ob = l4 * 16;

    const char* codes_src = (const char*)Bp + (size_t)n_tile * 65536;
    const char* z_src     = (const char*)Ap + (size_t)m_tile * 65536;

    #define STAGE(buf, kc)                                                        \
        do {                                                                      \
            const char* cs_ = codes_src + (size_t)(kc) * 8192;                    \
            const char* zs_ = z_src + (size_t)(kc) * 8192;                        \
            char* lb_ = lds + (buf) * 16384;                                      \
            gload16(cs_ + tid * 16, lb_ + tid * 16);                              \
            gload16(cs_ + 4096 + tid * 16, lb_ + 4096 + tid * 16);                \
            gload16(zs_ + tid * 16, lb_ + 8192 + tid * 16);                       \
            gload16(zs_ + 4096 + tid * 16, lb_ + 12288 + tid * 16);               \
        } while (0)

    #define COMPUTE(buf)                                                          \
        do {                                                                      \
            const char* base_ = lds + (buf) * 16384;                              \
            f16x8 la[4], lb[4];                                                   \
            _Pragma("unroll")                                                     \
            for (int f = 0; f < 4; ++f) {                                         \
                la[f] = *(const f16x8*)(base_ + rc[f] * 64 + (ob ^ xc[f]));       \
                lb[f] = *(const f16x8*)(base_ + 8192 + rz[f] * 64 + (ob ^ xz[f]));\
            }                                                                     \
            _Pragma("unroll")                                                     \
            for (int fm = 0; fm < 4; ++fm)                                        \
                _Pragma("unroll")                                                 \
                for (int fn = 0; fn < 4; ++fn)                                    \
                    acc[fm][fn] = __builtin_amdgcn_mfma_f32_16x16x32_f16(         \
                        la[fm], lb[fn], acc[fm][fn], 0, 0, 0);                    \
        } while (0)

    STAGE(0, 0);
    #pragma unroll
    for (int kc = 0; kc < 8; ++kc) {
        __syncthreads();                       // chunk kc landed; prev reads done
        if (kc < 7) STAGE((kc + 1) & 1, kc + 1);
        COMPUTE(kc & 1);
    }

    #undef STAGE
    #undef COMPUTE

    // epilogue: w = 0.5 - s_scaled*2^-12 (positive -> u32 order == float order);
    // clear low 6 mantissa bits, pack 6-bit in-tile idx, track top-2 via min/max.
    const int ktile = n_tile * 2 + wm;
    #pragma unroll
    for (int fn = 0; fn < 4; ++fn) {
        u32 m1 = 0xFFFFFFFFu, m2 = 0xFFFFFFFFu;
        #pragma unroll
        for (int fm = 0; fm < 4; ++fm) {
            #pragma unroll
            for (int rv = 0; rv < 4; ++rv) {
                float w = fmaf(acc[fm][fn][rv], -0x1p-12f, 0.5f);
                u32 p = (__float_as_uint(w) & ~63u) | (u32)(fm * 16 + l4 * 4 + rv);
                u32 t = m1 > p ? m1 : p;
                m1 = m1 < p ? m1 : p;
                m2 = m2 < t ? m2 : t;
            }
        }
        #pragma unroll
        for (int off = 16; off <= 32; off <<= 1) {
            u32 b1 = __shfl_xor(m1, off);
            u32 b2 = __shfl_xor(m2, off);
            u32 t = m1 > b1 ? m1 : b1;
            m1 = m1 < b1 ? m1 : b1;
            u32 s2 = m2 < b2 ? m2 : b2;
            m2 = s2 < t ? s2 : t;
        }
        if (l4 == 0) {
            int rowg = m_tile * 128 + wn * 64 + fn * 16 + l15;
            *(uint2*)(cand + (size_t)rowg * 256 + ktile * 2) = make_uint2(m1, m2);
        }
    }
}

// =============== pick: min + threshold + exact fp64 rescue + idx out =========
// wave per row. Fast path: exactly 1 candidate under thr -> it IS the argmin.
__global__ __launch_bounds__(256) void vq_pick(const u32* __restrict__ cand,
                                               const float* __restrict__ zT,
                                               const float* __restrict__ cb,
                                               const float* __restrict__ e2g,
                                               const float* __restrict__ zn2g,
                                               int* __restrict__ idxg,
                                               float* __restrict__ out) {
    const int lane = threadIdx.x & 63, wid = threadIdx.x >> 6;
    const int row = blockIdx.x * 4 + wid;
    const uint4 e = ((const uint4*)(cand + (size_t)row * 256))[lane];
    u32 m = e.x < e.y ? e.x : e.y;
    u32 mzw = e.z < e.w ? e.z : e.w;
    m = m < mzw ? m : mzw;
    #pragma unroll
    for (int off = 32; off >= 1; off >>= 1) {
        u32 o = __shfl_xor(m, off);
        m = o < m ? o : m;
    }
    const float thr = __uint_as_float(m & ~63u) + THRESH_T;
    const u32 ev[4] = { e.x, e.y, e.z, e.w };
    u64 msk[4];
    int tot = 0;
    #pragma unroll
    for (int j = 0; j < 4; ++j) {
        msk[j] = __ballot(__uint_as_float(ev[j] & ~63u) <= thr);
        tot += __popcll((unsigned long long)msk[j]);
    }
    int bk;
    if (tot == 1) {
        const int j = msk[0] ? 0 : (msk[1] ? 1 : (msk[2] ? 2 : 3));
        const int l = __ffsll((unsigned long long)msk[j]) - 1;
        const u32 val = __shfl(ev[j], l);
        bk = ((l * 4 + j) >> 1) * 64 + (int)(val & 63u);
    } else {
        const float4 zv = *(const float4*)(zT + (size_t)row * C_ + lane * 4);
        const float zn2a = zn2g[row];
        float bd = INFINITY;
        bk = 0x7fffffff;
        #pragma unroll
        for (int j = 0; j < 4; ++j) {
            u64 mj = msk[j];
            while (mj) {
                const int l = __ffsll((unsigned long long)mj) - 1;
                mj &= mj - 1;
                const u32 val = __shfl(ev[j], l);
                const int k = ((l * 4 + j) >> 1) * 64 + (int)(val & 63u);
                const float4 cv = *(const float4*)(cb + (size_t)k * C_ + lane * 4);
                double s = (double)zv.x * cv.x + (double)zv.y * cv.y
                         + (double)zv.z * cv.z + (double)zv.w * cv.w;
                #pragma unroll
                for (int off = 32; off >= 1; off >>= 1) s += __shfl_xor(s, off);
                const float sf = (float)s;
                const float d = (zn2a + e2g[k]) - 2.0f * sf;
                if (d < bd || (d == bd && k < bk)) { bd = d; bk = k; }
            }
        }
    }
    if (lane == 0) {
        idxg[row] = bk;
        out[8388609 + row] = (float)bk;
    }
}

// =============== z_q (STE mimic, float4) + per-block loss partials ===========
__global__ __launch_bounds__(256) void vq_zq_loss_kernel(const float* __restrict__ z,
                                                         const float* __restrict__ cb,
                                                         const int* __restrict__ idxg,
                                                         float* __restrict__ out,
                                                         double* __restrict__ partial) {
    double acc = 0.0;
    for (size_t i4 = (size_t)blockIdx.x * 256 + threadIdx.x; i4 < 2097152ULL;
         i4 += 2048ULL * 256ULL) {
        const size_t i = i4 * 4;
        const int hw = (int)(i & 4095);
        const int bc = (int)(i >> 12);
        const int c = bc & 255;
        const int b = bc >> 8;
        const int n = (b << 12) + hw;
        const float4 zv = *(const float4*)(z + i);
        const int k0 = idxg[n], k1 = idxg[n + 1], k2 = idxg[n + 2], k3 = idxg[n + 3];
        const float t0 = cb[(size_t)k0 * C_ + c] - zv.x;
        const float t1 = cb[(size_t)k1 * C_ + c] - zv.y;
        const float t2 = cb[(size_t)k2 * C_ + c] - zv.z;
        const float t3 = cb[(size_t)k3 * C_ + c] - zv.w;
        float4 o = { zv.x + t0, zv.y + t1, zv.z + t2, zv.w + t3 };
        *(float4*)(out + i) = o;
        acc += (double)t0 * t0 + (double)t1 * t1 + (double)t2 * t2 + (double)t3 * t3;
    }
    #pragma unroll
    for (int off = 32; off >= 1; off >>= 1) acc += __shfl_xor(acc, off);
    __shared__ double ls[4];
    const int lane = threadIdx.x & 63, wid = threadIdx.x >> 6;
    if (lane == 0) ls[wid] = acc;
    __syncthreads();
    if (threadIdx.x == 0) partial[blockIdx.x] = ls[0] + ls[1] + ls[2] + ls[3];
}

// =============== loss finalize (1 block) =====================================
__global__ __launch_bounds__(256) void vq_loss_final(const double* __restrict__ partial,
                                                     float* __restrict__ out) {
    double acc = 0.0;
    for (int j = threadIdx.x; j < 2048; j += 256) acc += partial[j];
    #pragma unroll
    for (int off = 32; off >= 1; off >>= 1) acc += __shfl_xor(acc, off);
    __shared__ double ls[4];
    const int lane = threadIdx.x & 63, wid = threadIdx.x >> 6;
    if (lane == 0) ls[wid] = acc;
    __syncthreads();
    if (threadIdx.x == 0)
        out[8388608] = (float)(1.25 * (ls[0] + ls[1] + ls[2] + ls[3]) / 8388608.0);
}

// =============== fallback fp64 path (round-1, used if ws too small) ==========
__global__ __launch_bounds__(256) void vq_e2_old(const float* __restrict__ cb,
                                                 float* __restrict__ e2g) {
    int lane = threadIdx.x & 63;
    int w = threadIdx.x >> 6;
    int k = blockIdx.x * 4 + w;
    const float4 v = *reinterpret_cast<const float4*>(cb + (size_t)k * C_ + lane * 4);
    double acc = (double)v.x * v.x + (double)v.y * v.y
               + (double)v.z * v.z + (double)v.w * v.w;
    #pragma unroll
    for (int off = 32; off >= 1; off >>= 1) acc += __shfl_xor(acc, off);
    if (lane == 0) e2g[k] = (float)acc;
}

__global__ __launch_bounds__(256) void vq_zn2_old(const float* __restrict__ z,
                                                  float* __restrict__ zn2g) {
    int n = blockIdx.x * 256 + threadIdx.x;
    int b = n >> 12;
    int hw = n & 4095;
    const float* p = z + (size_t)b * C_ * HW_ + hw;
    double acc = 0.0;
    #pragma unroll 8
    for (int c = 0; c < C_; ++c) {
        float v = p[(size_t)c * HW_];
        acc += (double)v * (double)v;
    }
    zn2g[n] = (float)acc;
}

__global__ __launch_bounds__(256) void vq_argmin_old(const float* __restrict__ z,
                                                     const float* __restrict__ cb,
                                                     const float* __restrict__ e2g,
                                                     const float* __restrict__ zn2g,
                                                     int* __restrict__ idxg) {
    __shared__ float zt[C_][32];
    __shared__ float et[64][64];
    const int tid = threadIdx.x;
    const int n0 = blockIdx.x * 32;
    const int b = n0 >> 12;
    const int hw0 = n0 & 4095;
    {
        const int nn = tid & 31;
        const int c8 = tid >> 5;
        #pragma unroll
        for (int j = 0; j < 32; ++j) {
            const int c = j * 8 + c8;
            zt[c][nn] = z[(size_t)(b * C_ + c) * HW_ + hw0 + nn];
        }
    }
    const int cg = tid & 15;
    const int rg = tid >> 4;
    const int r0 = rg * 2;
    __syncthreads();
    const float zn2a = zn2g[n0 + r0];
    const float zn2b = zn2g[n0 + r0 + 1];
    float dmin0 = INFINITY, dmin1 = INFINITY;
    int imin0 = 0, imin1 = 0;
    const int kk = tid >> 2;
    const int c4 = (tid & 3) * 16;
    for (int kt = 0; kt < K_; kt += 64) {
        double s00 = 0, s01 = 0, s02 = 0, s03 = 0;
        double s10 = 0, s11 = 0, s12 = 0, s13 = 0;
        for (int cc = 0; cc < C_; cc += 64) {
            __syncthreads();
            {
                const float* src = cb + (size_t)(kt + kk) * C_ + cc + c4;
                #pragma unroll
                for (int j = 0; j < 16; j += 4) {
                    const float4 v = *reinterpret_cast<const float4*>(src + j);
                    et[c4 + j + 0][kk] = v.x;
                    et[c4 + j + 1][kk] = v.y;
                    et[c4 + j + 2][kk] = v.z;
                    et[c4 + j + 3][kk] = v.w;
                }
            }
            __syncthreads();
            #pragma unroll 4
            for (int c2 = 0; c2 < 64; ++c2) {
                const float2 zv = *reinterpret_cast<const float2*>(&zt[cc + c2][r0]);
                const float4 ev = *reinterpret_cast<const float4*>(&et[c2][cg * 4]);
                const double z0 = (double)zv.x, z1 = (double)zv.y;
                s00 += z0 * ev.x; s01 += z0 * ev.y; s02 += z0 * ev.z; s03 += z0 * ev.w;
                s10 += z1 * ev.x; s11 += z1 * ev.y; s12 += z1 * ev.z; s13 += z1 * ev.w;
            }
        }
        const int kbase = kt + cg * 4;
        const float sf0[4] = {(float)s00, (float)s01, (float)s02, (float)s03};
        const float sf1[4] = {(float)s10, (float)s11, (float)s12, (float)s13};
        #pragma unroll
        for (int j = 0; j < 4; ++j) {
            const int k = kbase + j;
            const float e2k = e2g[k];
            const float d0 = (zn2a + e2k) - 2.0f * sf0[j];
            const float d1 = (zn2b + e2k) - 2.0f * sf1[j];
            if (d0 < dmin0) { dmin0 = d0; imin0 = k; }
            if (d1 < dmin1) { dmin1 = d1; imin1 = k; }
        }
    }
    #pragma unroll
    for (int off = 8; off >= 1; off >>= 1) {
        const float od0 = __shfl_xor(dmin0, off);
        const int   oi0 = __shfl_xor(imin0, off);
        const float od1 = __shfl_xor(dmin1, off);
        const int   oi1 = __shfl_xor(imin1, off);
        if (od0 < dmin0 || (od0 == dmin0 && oi0 < imin0)) { dmin0 = od0; imin0 = oi0; }
        if (od1 < dmin1 || (od1 == dmin1 && oi1 < imin1)) { dmin1 = od1; imin1 = oi1; }
    }
    if (cg == 0) {
        idxg[n0 + r0]     = imin0;
        idxg[n0 + r0 + 1] = imin1;
    }
}

__global__ __launch_bounds__(256) void vq_final_old(const int* __restrict__ idxg,
                                                    float* __restrict__ out) {
    const int i = blockIdx.x * 256 + threadIdx.x;
    out[8388609 + i] = (float)idxg[i];
}

extern "C" void kernel_launch(void* const* d_in, const int* in_sizes, int n_in,
                              void* d_out, int out_size, void* d_ws, size_t ws_size,
                              hipStream_t stream) {
    const float* z  = (const float*)d_in[0];
    const float* cb = (const float*)d_in[1];
    float* out = (float*)d_out;
    char* ws = (char*)d_ws;

    double* lossp = (double*)(ws + O_LOSSP);
    float*  e2g  = (float*)(ws + O_E2);
    float*  zn2g = (float*)(ws + O_ZN2);
    int*    idxg = (int*)(ws + O_IDX);

    if (ws_size >= WS_NEED) {
        float* zT   = (float*)(ws + O_ZT);
        u16*   Ap   = (u16*)(ws + O_AP);
        u16*   Bp   = (u16*)(ws + O_BP);
        u32*   cand = (u32*)(ws + O_CAND);

        hipLaunchKernelGGL(vq_prep_cb, dim3(128), dim3(256), 0, stream, cb, Bp, e2g);
        hipLaunchKernelGGL(vq_prep_z, dim3(512), dim3(256), 0, stream, z, zT, Ap, zn2g);
        hipLaunchKernelGGL(vq_gemm_top2, dim3(16384), dim3(256), 0, stream, Ap, Bp, cand);
        hipLaunchKernelGGL(vq_pick, dim3(N_ / 4), dim3(256), 0, stream,
                           cand, zT, cb, e2g, zn2g, idxg, out);
    } else {
        hipLaunchKernelGGL(vq_e2_old, dim3(K_ / 4), dim3(256), 0, stream, cb, e2g);
        hipLaunchKernelGGL(vq_zn2_old, dim3(N_ / 256), dim3(256), 0, stream, z, zn2g);
        hipLaunchKernelGGL(vq_argmin_old, dim3(N_ / 32), dim3(256), 0, stream,
                           z, cb, e2g, zn2g, idxg);
        hipLaunchKernelGGL(vq_final_old, dim3(N_ / 256), dim3(256), 0, stream, idxg, out);
    }

    hipLaunchKernelGGL(vq_zq_loss_kernel, dim3(2048), dim3(256), 0, stream,
                       z, cb, idxg, out, lossp);
    hipLaunchKernelGGL(vq_loss_final, dim3(1), dim3(256), 0, stream, lossp, out);
}